// Round 1
// baseline (451.951 us; speedup 1.0000x reference)
//
#include <hip/hip_runtime.h>

// TransformerBlock on MI355X: LN1 -> QKV -> causal MHA -> O-proj+res -> LN2 -> FFN+res
// All matmuls in bf16 MFMA (16x16x32), fp32 accumulate. Threshold 0.1 >> bf16 error.

typedef __bf16 bf16_t;
typedef __attribute__((ext_vector_type(8))) __bf16 bf16x8;
typedef __attribute__((ext_vector_type(4))) __bf16 bf16x4;
typedef __attribute__((ext_vector_type(4))) float f32x4;

#define B_DIM 2
#define S_DIM 2048
#define E_DIM 1024
#define H_DIM 16
#define DH_DIM 64

// ---------------- LayerNorm: fp32 in -> bf16 out (one block per row) -------------
__global__ __launch_bounds__(256) void ln_kernel(
    const float* __restrict__ x, const float* __restrict__ g,
    const float* __restrict__ bv, bf16_t* __restrict__ out)
{
  const int row = blockIdx.x;
  const int t = threadIdx.x;
  const float* xr = x + (size_t)row * E_DIM;
  float4 v = *(const float4*)&xr[t * 4];
  float s  = v.x + v.y + v.z + v.w;
  float s2 = v.x*v.x + v.y*v.y + v.z*v.z + v.w*v.w;
#pragma unroll
  for (int m = 1; m < 64; m <<= 1) {
    s  += __shfl_xor(s,  m, 64);
    s2 += __shfl_xor(s2, m, 64);
  }
  __shared__ float red[8];
  const int wid = t >> 6, lane = t & 63;
  if (lane == 0) { red[wid] = s; red[4 + wid] = s2; }
  __syncthreads();
  s  = red[0] + red[1] + red[2] + red[3];
  s2 = red[4] + red[5] + red[6] + red[7];
  const float mu  = s * (1.f / E_DIM);
  const float var = s2 * (1.f / E_DIM) - mu * mu;
  const float rs  = rsqrtf(var + 1e-5f);
  float4 gg = *(const float4*)&g[t * 4];
  float4 bb = *(const float4*)&bv[t * 4];
  bf16x4 o;
  o[0] = (bf16_t)((v.x - mu) * rs * gg.x + bb.x);
  o[1] = (bf16_t)((v.y - mu) * rs * gg.y + bb.y);
  o[2] = (bf16_t)((v.z - mu) * rs * gg.z + bb.z);
  o[3] = (bf16_t)((v.w - mu) * rs * gg.w + bb.w);
  *(bf16x4*)&out[(size_t)row * E_DIM + t * 4] = o;
}

// -------- generic transpose+cast: src [R][C] f32 -> dst [C][R] bf16 --------------
__global__ __launch_bounds__(256) void transpose_cast(
    const float* __restrict__ src, bf16_t* __restrict__ dst, int R, int C)
{
  __shared__ float tile[64][65];
  const int c0 = blockIdx.x * 64, r0 = blockIdx.y * 64;
  const int t = threadIdx.x;
  const int rr = t >> 2;
#pragma unroll
  for (int u = 0; u < 4; u++) {
    const int cc = (t & 3) * 4 + u * 16;
    float4 f = *(const float4*)&src[(size_t)(r0 + rr) * C + c0 + cc];
    tile[rr][cc + 0] = f.x; tile[rr][cc + 1] = f.y;
    tile[rr][cc + 2] = f.z; tile[rr][cc + 3] = f.w;
  }
  __syncthreads();
  const int oc = t >> 2;
#pragma unroll
  for (int u = 0; u < 4; u++) {
    const int orr = (t & 3) * 4 + u * 16;
    bf16x4 w;
    w[0] = (bf16_t)tile[orr + 0][oc];
    w[1] = (bf16_t)tile[orr + 1][oc];
    w[2] = (bf16_t)tile[orr + 2][oc];
    w[3] = (bf16_t)tile[orr + 3][oc];
    *(bf16x4*)&dst[(size_t)(c0 + oc) * R + r0 + orr] = w;
  }
}

// -------- QKV weight pack: W{q,k,v}[H][E][DH] f32 -> WqkvT[m*1024+h*64+d][e] bf16 --
__global__ __launch_bounds__(256) void qkv_transpose(
    const float* __restrict__ Wq, const float* __restrict__ Wk,
    const float* __restrict__ Wv, bf16_t* __restrict__ dstT)
{
  const int m = blockIdx.y >> 4, h = blockIdx.y & 15;
  const float* src = (m == 0 ? Wq : (m == 1 ? Wk : Wv)) + (size_t)h * E_DIM * DH_DIM;
  const int e0 = blockIdx.x * 64;
  __shared__ float tile[64][65];
  const int t = threadIdx.x;
  const int rr = t >> 2;
#pragma unroll
  for (int u = 0; u < 4; u++) {
    const int cc = (t & 3) * 4 + u * 16;
    float4 f = *(const float4*)&src[(size_t)(e0 + rr) * DH_DIM + cc];
    tile[rr][cc + 0] = f.x; tile[rr][cc + 1] = f.y;
    tile[rr][cc + 2] = f.z; tile[rr][cc + 3] = f.w;
  }
  __syncthreads();
  const int oc = t >> 2;  // d index 0..63
  const size_t drow = (size_t)(m * 1024 + h * 64 + oc) * E_DIM;
#pragma unroll
  for (int u = 0; u < 4; u++) {
    const int orr = (t & 3) * 4 + u * 16;
    bf16x4 w;
    w[0] = (bf16_t)tile[orr + 0][oc];
    w[1] = (bf16_t)tile[orr + 1][oc];
    w[2] = (bf16_t)tile[orr + 2][oc];
    w[3] = (bf16_t)tile[orr + 3][oc];
    *(bf16x4*)&dstT[drow + e0 + orr] = w;
  }
}

// ---------------- MFMA GEMM: C = A[M,K] * Bt[N,K]^T, templated epilogue ----------
constexpr int EPI_QKV = 0, EPI_BIAS_RES = 1, EPI_BIAS_RELU = 2;

template <int EPI>
__global__ __launch_bounds__(256) void gemm_kernel(
    const bf16_t* __restrict__ A, const bf16_t* __restrict__ Bt,
    int M, int N, int K,
    const float* __restrict__ bias, const float* __restrict__ resid,
    float* __restrict__ outF, bf16_t* __restrict__ outB,
    bf16_t* __restrict__ qo, bf16_t* __restrict__ ko, bf16_t* __restrict__ vo)
{
  __shared__ bf16_t As[128 * 32];
  __shared__ bf16_t Bs[128 * 32];
  const int m0 = blockIdx.x * 128, n0 = blockIdx.y * 128;
  const int tid = threadIdx.x, lane = tid & 63, wid = tid >> 6;
  const int wr = wid >> 1, wc = wid & 1;
  const int lr = lane & 15, lg = lane >> 4;

  const int rS = tid >> 2, k8 = (tid & 3) * 8;
  const bf16_t* Ag0 = A  + (size_t)(m0 + rS)      * K + k8;
  const bf16_t* Ag1 = A  + (size_t)(m0 + rS + 64) * K + k8;
  const bf16_t* Bg0 = Bt + (size_t)(n0 + rS)      * K + k8;
  const bf16_t* Bg1 = Bt + (size_t)(n0 + rS + 64) * K + k8;

  const f32x4 z4 = {0.f, 0.f, 0.f, 0.f};
  f32x4 acc[4][4];
#pragma unroll
  for (int i = 0; i < 4; i++)
#pragma unroll
    for (int j = 0; j < 4; j++) acc[i][j] = z4;

  for (int k0 = 0; k0 < K; k0 += 32) {
    bf16x8 a0 = *(const bf16x8*)(Ag0 + k0);
    bf16x8 a1 = *(const bf16x8*)(Ag1 + k0);
    bf16x8 b0 = *(const bf16x8*)(Bg0 + k0);
    bf16x8 b1 = *(const bf16x8*)(Bg1 + k0);
    __syncthreads();  // prev-iter LDS reads done before overwrite
    *(bf16x8*)&As[rS * 32 + k8]        = a0;
    *(bf16x8*)&As[(rS + 64) * 32 + k8] = a1;
    *(bf16x8*)&Bs[rS * 32 + k8]        = b0;
    *(bf16x8*)&Bs[(rS + 64) * 32 + k8] = b1;
    __syncthreads();
    bf16x8 af[4], bfr[4];
#pragma unroll
    for (int i = 0; i < 4; i++)
      af[i]  = *(const bf16x8*)&As[(wr * 64 + i * 16 + lr) * 32 + lg * 8];
#pragma unroll
    for (int j = 0; j < 4; j++)
      bfr[j] = *(const bf16x8*)&Bs[(wc * 64 + j * 16 + lr) * 32 + lg * 8];
#pragma unroll
    for (int i = 0; i < 4; i++)
#pragma unroll
      for (int j = 0; j < 4; j++)
        acc[i][j] = __builtin_amdgcn_mfma_f32_16x16x32_bf16(af[i], bfr[j], acc[i][j], 0, 0, 0);
  }

#pragma unroll
  for (int i = 0; i < 4; i++) {
#pragma unroll
    for (int j = 0; j < 4; j++) {
#pragma unroll
      for (int r = 0; r < 4; r++) {
        const int m = m0 + wr * 64 + i * 16 + lg * 4 + r;
        const int n = n0 + wc * 64 + j * 16 + lr;
        const float val = acc[i][j][r];
        if constexpr (EPI == EPI_QKV) {
          const int tsel = n >> 10, h = (n >> 6) & 15, d = n & 63;
          const int b = m >> 11, s = m & 2047;
          const size_t idx = ((size_t)((b * H_DIM + h) * S_DIM + s)) * DH_DIM + d;
          if (tsel == 0)      qo[idx] = (bf16_t)(val * 0.03125f);  // fold E^-0.5 = 1/32
          else if (tsel == 1) ko[idx] = (bf16_t)val;
          else                vo[idx] = (bf16_t)val;
        } else if constexpr (EPI == EPI_BIAS_RES) {
          outF[(size_t)m * N + n] = val + bias[n] + resid[(size_t)m * N + n];
        } else {
          const float u = val + bias[n];
          outB[(size_t)m * N + n] = (bf16_t)(u > 0.f ? u : 0.f);
        }
      }
    }
  }
}

// ---------------- causal flash attention, bf16 MFMA --------------------------------
// grid: (S/64 q-tiles, B*H). block: 256 = 4 waves, wave w owns q rows [q0b+16w, +16)
__global__ __launch_bounds__(256) void attn_kernel(
    const bf16_t* __restrict__ Q, const bf16_t* __restrict__ K,
    const bf16_t* __restrict__ V, bf16_t* __restrict__ O)
{
  __shared__ bf16_t Ks[32 * 64];       // [t][d]
  __shared__ bf16_t Vst[64 * 32];      // [d][t]
  __shared__ bf16_t Ps[4][16 * 32];    // per-wave P tile [q][t]

  const int bh = blockIdx.y;
  const int q0b = blockIdx.x * 64;
  const int tid = threadIdx.x;
  const int wid = tid >> 6, lane = tid & 63;
  const int lr = lane & 15, lg = lane >> 4;
  const int q0w = q0b + wid * 16;

  const bf16_t* Qp = Q + (size_t)bh * S_DIM * DH_DIM;
  const bf16_t* Kp = K + (size_t)bh * S_DIM * DH_DIM;
  const bf16_t* Vp = V + (size_t)bh * S_DIM * DH_DIM;

  bf16x8 aq[2];
#pragma unroll
  for (int c = 0; c < 2; c++)
    aq[c] = *(const bf16x8*)&Qp[(size_t)(q0w + lr) * DH_DIM + c * 32 + lg * 8];

  const f32x4 z4 = {0.f, 0.f, 0.f, 0.f};
  f32x4 Ot[4];
  float mrow[4], lrow[4];
#pragma unroll
  for (int r = 0; r < 4; r++) { mrow[r] = -1e38f; lrow[r] = 0.f; }
#pragma unroll
  for (int d4 = 0; d4 < 4; d4++) Ot[d4] = z4;

  const int srow = tid >> 3, sc8 = (tid & 7) * 8;
  const int nchunk = blockIdx.x * 2 + 2;  // t chunks of 32 covering [0, q0b+64)

  for (int tc = 0; tc < nchunk; ++tc) {
    const int t0 = tc * 32;
    bf16x8 kv = *(const bf16x8*)&Kp[(size_t)(t0 + srow) * DH_DIM + sc8];
    bf16x8 vv = *(const bf16x8*)&Vp[(size_t)(t0 + srow) * DH_DIM + sc8];
    __syncthreads();  // prev-iter LDS reads done
    *(bf16x8*)&Ks[srow * 64 + sc8] = kv;
#pragma unroll
    for (int j = 0; j < 8; j++) Vst[(sc8 + j) * 32 + srow] = vv[j];
    __syncthreads();

    // scores: S[q][t] = Q . K^T   (scale already folded into Q)
    f32x4 sc[2];
#pragma unroll
    for (int j = 0; j < 2; j++) {
      f32x4 s = z4;
#pragma unroll
      for (int c = 0; c < 2; c++) {
        bf16x8 bk = *(const bf16x8*)&Ks[(j * 16 + lr) * 64 + c * 32 + lg * 8];
        s = __builtin_amdgcn_mfma_f32_16x16x32_bf16(aq[c], bk, s, 0, 0, 0);
      }
      sc[j] = s;
    }
    // causal mask: C layout row=(lg*4+r), col=lr
#pragma unroll
    for (int j = 0; j < 2; j++)
#pragma unroll
      for (int r = 0; r < 4; r++) {
        const int tt = t0 + j * 16 + lr;
        const int qq = q0w + lg * 4 + r;
        if (tt > qq) sc[j][r] = -1e30f;
      }
    // online softmax
    float tmax[4], tsum[4], fsc[4];
#pragma unroll
    for (int r = 0; r < 4; r++) tmax[r] = fmaxf(sc[0][r], sc[1][r]);
#pragma unroll
    for (int m = 1; m < 16; m <<= 1)
#pragma unroll
      for (int r = 0; r < 4; r++) tmax[r] = fmaxf(tmax[r], __shfl_xor(tmax[r], m, 64));
#pragma unroll
    for (int r = 0; r < 4; r++) {
      const float mn = fmaxf(mrow[r], tmax[r]);
      fsc[r] = __expf(mrow[r] - mn);
      mrow[r] = mn;
      tsum[r] = 0.f;
    }
#pragma unroll
    for (int j = 0; j < 2; j++)
#pragma unroll
      for (int r = 0; r < 4; r++) {
        const float p = __expf(sc[j][r] - mrow[r]);
        sc[j][r] = p;
        tsum[r] += p;
      }
#pragma unroll
    for (int m = 1; m < 16; m <<= 1)
#pragma unroll
      for (int r = 0; r < 4; r++) tsum[r] += __shfl_xor(tsum[r], m, 64);
#pragma unroll
    for (int r = 0; r < 4; r++) lrow[r] = lrow[r] * fsc[r] + tsum[r];
#pragma unroll
    for (int d4 = 0; d4 < 4; d4++)
#pragma unroll
      for (int r = 0; r < 4; r++) Ot[d4][r] *= fsc[r];
    // P -> LDS (wave-private), read back in A-operand layout
#pragma unroll
    for (int j = 0; j < 2; j++)
#pragma unroll
      for (int r = 0; r < 4; r++)
        Ps[wid][(lg * 4 + r) * 32 + j * 16 + lr] = (bf16_t)sc[j][r];
    bf16x8 pa = *(const bf16x8*)&Ps[wid][lr * 32 + lg * 8];
#pragma unroll
    for (int d4 = 0; d4 < 4; d4++) {
      bf16x8 bvv = *(const bf16x8*)&Vst[(d4 * 16 + lr) * 32 + lg * 8];
      Ot[d4] = __builtin_amdgcn_mfma_f32_16x16x32_bf16(pa, bvv, Ot[d4], 0, 0, 0);
    }
  }

  const int b = bh >> 4, h = bh & 15;
#pragma unroll
  for (int r = 0; r < 4; r++) {
    const float inv = 1.f / lrow[r];
    const int s = q0w + lg * 4 + r;
    const size_t base = ((size_t)(b * S_DIM + s)) * E_DIM + h * DH_DIM;
#pragma unroll
    for (int d4 = 0; d4 < 4; d4++)
      O[base + d4 * 16 + lr] = (bf16_t)(Ot[d4][r] * inv);
  }
}

// ---------------- launcher ---------------------------------------------------------
extern "C" void kernel_launch(void* const* d_in, const int* in_sizes, int n_in,
                              void* d_out, int out_size, void* d_ws, size_t ws_size,
                              hipStream_t stream)
{
  const float* x    = (const float*)d_in[0];
  const float* ln1g = (const float*)d_in[1];
  const float* ln1b = (const float*)d_in[2];
  const float* Wq   = (const float*)d_in[3];
  const float* Wk   = (const float*)d_in[4];
  const float* Wv   = (const float*)d_in[5];
  const float* Wo   = (const float*)d_in[6];
  const float* bo   = (const float*)d_in[7];
  const float* ln2g = (const float*)d_in[8];
  const float* ln2b = (const float*)d_in[9];
  const float* W1   = (const float*)d_in[10];
  const float* b1   = (const float*)d_in[11];
  const float* W2   = (const float*)d_in[12];
  const float* b2   = (const float*)d_in[13];

  char* ws = (char*)d_ws;
  bf16_t* WqkvT = (bf16_t*)(ws + 0);          //  6.29 MB  [3072][1024]
  bf16_t* WoT   = (bf16_t*)(ws + 6291456);    //  2.10 MB  [1024][1024]
  bf16_t* W1T   = (bf16_t*)(ws + 8388608);    //  8.39 MB  [4096][1024]
  bf16_t* W2T   = (bf16_t*)(ws + 16777216);   //  8.39 MB  [1024][4096]
  bf16_t* h1    = (bf16_t*)(ws + 25165824);   //  8.39 MB  [4096][1024]
  bf16_t* qb    = (bf16_t*)(ws + 33554432);   //  8.39 MB  [B,H,S,DH]
  bf16_t* kb    = (bf16_t*)(ws + 41943040);   //  8.39 MB
  bf16_t* vb    = (bf16_t*)(ws + 50331648);   //  8.39 MB
  bf16_t* attnb = (bf16_t*)(ws + 58720256);   //  8.39 MB  [4096][1024] (head-concat)
  float*  xmid  = (float* )(ws + 67108864);   // 16.78 MB  [4096][1024] f32
  bf16_t* h2    = (bf16_t*)(ws + 83886080);   //  8.39 MB  -> total 92.3 MB
  bf16_t* ff1   = (bf16_t*)(ws + 25165824);   // 33.55 MB alias over h1/q/k/v (dead)

  qkv_transpose<<<dim3(16, 48), 256, 0, stream>>>(Wq, Wk, Wv, WqkvT);
  transpose_cast<<<dim3(16, 16), 256, 0, stream>>>(Wo, WoT, 1024, 1024);
  transpose_cast<<<dim3(64, 16), 256, 0, stream>>>(W1, W1T, 1024, 4096);
  transpose_cast<<<dim3(16, 64), 256, 0, stream>>>(W2, W2T, 4096, 1024);

  ln_kernel<<<4096, 256, 0, stream>>>(x, ln1g, ln1b, h1);
  gemm_kernel<EPI_QKV><<<dim3(32, 24), 256, 0, stream>>>(
      h1, WqkvT, 4096, 3072, 1024, nullptr, nullptr, nullptr, nullptr, qb, kb, vb);
  attn_kernel<<<dim3(32, 32), 256, 0, stream>>>(qb, kb, vb, attnb);
  gemm_kernel<EPI_BIAS_RES><<<dim3(32, 8), 256, 0, stream>>>(
      attnb, WoT, 4096, 1024, 1024, bo, x, xmid, nullptr, nullptr, nullptr, nullptr);
  ln_kernel<<<4096, 256, 0, stream>>>(xmid, ln2g, ln2b, h2);
  gemm_kernel<EPI_BIAS_RELU><<<dim3(32, 32), 256, 0, stream>>>(
      h2, W1T, 4096, 4096, 1024, b1, nullptr, nullptr, ff1, nullptr, nullptr, nullptr);
  gemm_kernel<EPI_BIAS_RES><<<dim3(32, 8), 256, 0, stream>>>(
      ff1, W2T, 4096, 1024, 4096, b2, xmid, (float*)d_out, nullptr, nullptr, nullptr, nullptr);

  (void)in_sizes; (void)n_in; (void)out_size; (void)ws_size;
}

// Round 2
// 340.820 us; speedup vs baseline: 1.3261x; 1.3261x over previous
//
#include <hip/hip_runtime.h>

// TransformerBlock on MI355X: LN1 -> QKV -> causal MHA -> O-proj+res -> LN2 -> FFN+res
// All matmuls bf16 MFMA 16x16x32, fp32 accumulate.
// R2: attn rewritten (swapped QK^T, in-lane softmax, swizzled LDS, balanced causal
// dispatch); GEMM staging via global_load_lds width=16 (m97 structure).

typedef __bf16 bf16_t;
typedef __attribute__((ext_vector_type(8))) __bf16 bf16x8;
typedef __attribute__((ext_vector_type(4))) __bf16 bf16x4;
typedef __attribute__((ext_vector_type(4))) float f32x4;

#define B_DIM 2
#define S_DIM 2048
#define E_DIM 1024
#define H_DIM 16
#define DH_DIM 64

#define GLD16(gp, lp) __builtin_amdgcn_global_load_lds( \
    (const __attribute__((address_space(1))) void*)(gp), \
    (__attribute__((address_space(3))) void*)(lp), 16, 0, 0)

// ---------------- LayerNorm: fp32 in -> bf16 out (one block per row) -------------
__global__ __launch_bounds__(256) void ln_kernel(
    const float* __restrict__ x, const float* __restrict__ g,
    const float* __restrict__ bv, bf16_t* __restrict__ out)
{
  const int row = blockIdx.x;
  const int t = threadIdx.x;
  const float* xr = x + (size_t)row * E_DIM;
  float4 v = *(const float4*)&xr[t * 4];
  float s  = v.x + v.y + v.z + v.w;
  float s2 = v.x*v.x + v.y*v.y + v.z*v.z + v.w*v.w;
#pragma unroll
  for (int m = 1; m < 64; m <<= 1) {
    s  += __shfl_xor(s,  m, 64);
    s2 += __shfl_xor(s2, m, 64);
  }
  __shared__ float red[8];
  const int wid = t >> 6, lane = t & 63;
  if (lane == 0) { red[wid] = s; red[4 + wid] = s2; }
  __syncthreads();
  s  = red[0] + red[1] + red[2] + red[3];
  s2 = red[4] + red[5] + red[6] + red[7];
  const float mu  = s * (1.f / E_DIM);
  const float var = s2 * (1.f / E_DIM) - mu * mu;
  const float rs  = rsqrtf(var + 1e-5f);
  float4 gg = *(const float4*)&g[t * 4];
  float4 bb = *(const float4*)&bv[t * 4];
  bf16x4 o;
  o[0] = (bf16_t)((v.x - mu) * rs * gg.x + bb.x);
  o[1] = (bf16_t)((v.y - mu) * rs * gg.y + bb.y);
  o[2] = (bf16_t)((v.z - mu) * rs * gg.z + bb.z);
  o[3] = (bf16_t)((v.w - mu) * rs * gg.w + bb.w);
  *(bf16x4*)&out[(size_t)row * E_DIM + t * 4] = o;
}

// -------- generic transpose+cast: src [R][C] f32 -> dst [C][R] bf16 --------------
__global__ __launch_bounds__(256) void transpose_cast(
    const float* __restrict__ src, bf16_t* __restrict__ dst, int R, int C)
{
  __shared__ float tile[64][65];
  const int c0 = blockIdx.x * 64, r0 = blockIdx.y * 64;
  const int t = threadIdx.x;
  const int rr = t >> 2;
#pragma unroll
  for (int u = 0; u < 4; u++) {
    const int cc = (t & 3) * 4 + u * 16;
    float4 f = *(const float4*)&src[(size_t)(r0 + rr) * C + c0 + cc];
    tile[rr][cc + 0] = f.x; tile[rr][cc + 1] = f.y;
    tile[rr][cc + 2] = f.z; tile[rr][cc + 3] = f.w;
  }
  __syncthreads();
  const int oc = t >> 2;
#pragma unroll
  for (int u = 0; u < 4; u++) {
    const int orr = (t & 3) * 4 + u * 16;
    bf16x4 w;
    w[0] = (bf16_t)tile[orr + 0][oc];
    w[1] = (bf16_t)tile[orr + 1][oc];
    w[2] = (bf16_t)tile[orr + 2][oc];
    w[3] = (bf16_t)tile[orr + 3][oc];
    *(bf16x4*)&dst[(size_t)(c0 + oc) * R + r0 + orr] = w;
  }
}

// -------- QKV weight pack: W{q,k,v}[H][E][DH] f32 -> WqkvT[m*1024+h*64+d][e] bf16 --
__global__ __launch_bounds__(256) void qkv_transpose(
    const float* __restrict__ Wq, const float* __restrict__ Wk,
    const float* __restrict__ Wv, bf16_t* __restrict__ dstT)
{
  const int m = blockIdx.y >> 4, h = blockIdx.y & 15;
  const float* src = (m == 0 ? Wq : (m == 1 ? Wk : Wv)) + (size_t)h * E_DIM * DH_DIM;
  const int e0 = blockIdx.x * 64;
  __shared__ float tile[64][65];
  const int t = threadIdx.x;
  const int rr = t >> 2;
#pragma unroll
  for (int u = 0; u < 4; u++) {
    const int cc = (t & 3) * 4 + u * 16;
    float4 f = *(const float4*)&src[(size_t)(e0 + rr) * DH_DIM + cc];
    tile[rr][cc + 0] = f.x; tile[rr][cc + 1] = f.y;
    tile[rr][cc + 2] = f.z; tile[rr][cc + 3] = f.w;
  }
  __syncthreads();
  const int oc = t >> 2;  // d index 0..63
  const size_t drow = (size_t)(m * 1024 + h * 64 + oc) * E_DIM;
#pragma unroll
  for (int u = 0; u < 4; u++) {
    const int orr = (t & 3) * 4 + u * 16;
    bf16x4 w;
    w[0] = (bf16_t)tile[orr + 0][oc];
    w[1] = (bf16_t)tile[orr + 1][oc];
    w[2] = (bf16_t)tile[orr + 2][oc];
    w[3] = (bf16_t)tile[orr + 3][oc];
    *(bf16x4*)&dstT[drow + e0 + orr] = w;
  }
}

// ---------------- MFMA GEMM: C = A[M,K] * Bt[N,K]^T, templated epilogue ----------
constexpr int EPI_QKV = 0, EPI_BIAS_RES = 1, EPI_BIAS_RELU = 2;

// fold E^-0.5 (=1/32) and log2(e) into Q so softmax can use exp2 directly
#define Q_SCALE 0.0450842120f

template <int EPI>
__global__ __launch_bounds__(256) void gemm_kernel(
    const bf16_t* __restrict__ A, const bf16_t* __restrict__ Bt,
    int M, int N, int K,
    const float* __restrict__ bias, const float* __restrict__ resid,
    float* __restrict__ outF, bf16_t* __restrict__ outB,
    bf16_t* __restrict__ qo, bf16_t* __restrict__ ko, bf16_t* __restrict__ vo)
{
  __shared__ bf16_t As[128 * 32];
  __shared__ bf16_t Bs[128 * 32];
  const int m0 = blockIdx.x * 128, n0 = blockIdx.y * 128;
  const int tid = threadIdx.x, lane = tid & 63, wid = tid >> 6;
  const int wr = wid >> 1, wc = wid & 1;
  const int lr = lane & 15, lg = lane >> 4;

  // global_load_lds lane map: LDS dest = base + lane*16B; linear row-major [row][32]
  // => lane covers (row = base_row + lane/4, k8 = (lane&3)*8 elements). m97 pattern.
  const int rl = lane >> 2, k8 = (lane & 3) * 8;

  const f32x4 z4 = {0.f, 0.f, 0.f, 0.f};
  f32x4 acc[4][4];
#pragma unroll
  for (int i = 0; i < 4; i++)
#pragma unroll
    for (int j = 0; j < 4; j++) acc[i][j] = z4;

  for (int k0 = 0; k0 < K; k0 += 32) {
    __syncthreads();  // prev-iter LDS reads done before DMA overwrite
#pragma unroll
    for (int q = 0; q < 2; q++) {
      const int row = q * 64 + wid * 16 + rl;
      GLD16(A  + (size_t)(m0 + row) * K + k0 + k8, &As[(q * 64 + wid * 16) * 32]);
      GLD16(Bt + (size_t)(n0 + row) * K + k0 + k8, &Bs[(q * 64 + wid * 16) * 32]);
    }
    __syncthreads();  // compiler drains vmcnt before s_barrier
    bf16x8 af[4], bfr[4];
#pragma unroll
    for (int i = 0; i < 4; i++)
      af[i]  = *(const bf16x8*)&As[(wr * 64 + i * 16 + lr) * 32 + lg * 8];
#pragma unroll
    for (int j = 0; j < 4; j++)
      bfr[j] = *(const bf16x8*)&Bs[(wc * 64 + j * 16 + lr) * 32 + lg * 8];
#pragma unroll
    for (int i = 0; i < 4; i++)
#pragma unroll
      for (int j = 0; j < 4; j++)
        acc[i][j] = __builtin_amdgcn_mfma_f32_16x16x32_bf16(af[i], bfr[j], acc[i][j], 0, 0, 0);
  }

#pragma unroll
  for (int i = 0; i < 4; i++) {
#pragma unroll
    for (int j = 0; j < 4; j++) {
#pragma unroll
      for (int r = 0; r < 4; r++) {
        const int m = m0 + wr * 64 + i * 16 + lg * 4 + r;
        const int n = n0 + wc * 64 + j * 16 + lr;
        const float val = acc[i][j][r];
        if constexpr (EPI == EPI_QKV) {
          const int tsel = n >> 10, h = (n >> 6) & 15, d = n & 63;
          const int b = m >> 11, s = m & 2047;
          const size_t idx = ((size_t)((b * H_DIM + h) * S_DIM + s)) * DH_DIM + d;
          if (tsel == 0)      qo[idx] = (bf16_t)(val * Q_SCALE);
          else if (tsel == 1) ko[idx] = (bf16_t)val;
          else                vo[idx] = (bf16_t)val;
        } else if constexpr (EPI == EPI_BIAS_RES) {
          outF[(size_t)m * N + n] = val + bias[n] + resid[(size_t)m * N + n];
        } else {
          const float u = val + bias[n];
          outB[(size_t)m * N + n] = (bf16_t)(u > 0.f ? u : 0.f);
        }
      }
    }
  }
}

// ---------------- causal flash attention, swapped-QK^T, bf16 MFMA ------------------
// grid: (32 q-tiles REVERSED for causal load balance, B*H). block 256 = 4 waves.
// Wave w owns q rows [qt*64 + 16w, +16). KVBLK = 64.
// Swapped QK^T: S^T = mfma(K_frag, Q_frag) -> lane (lr,lg) holds q=lr,
// t = t0 + 16j + lg*4 + r  => row softmax is in-lane + 2 shfl_xor.
__global__ __launch_bounds__(256) void attn_kernel(
    const bf16_t* __restrict__ Q, const bf16_t* __restrict__ K,
    const bf16_t* __restrict__ V, bf16_t* __restrict__ O)
{
  __shared__ bf16_t Ks[64 * 64];      // [t][d], swizzled: slot ^= (t&7)
  __shared__ bf16_t Vst[64 * 64];     // [d][t], swizzled: slot ^= (d&7)^((d>>3)&7)
  __shared__ bf16_t Ps[4][16 * 64];   // per-wave [q][t], swizzled: slot ^= (q&7)

  const int bh = blockIdx.y;
  const int qt = (int)gridDim.x - 1 - (int)blockIdx.x;  // heavy tiles first
  const int q0b = qt * 64;
  const int tid = threadIdx.x;
  const int wid = tid >> 6, lane = tid & 63;
  const int lr = lane & 15, lg = lane >> 4;
  const int q0w = q0b + wid * 16;

  const bf16_t* Qp = Q + (size_t)bh * S_DIM * DH_DIM;
  const bf16_t* Kp = K + (size_t)bh * S_DIM * DH_DIM;
  const bf16_t* Vp = V + (size_t)bh * S_DIM * DH_DIM;

  // Q as B-fragment: lane (lr=q, lg) holds Q[q0w+lr][c*32 + lg*8 ..]
  bf16x8 bq[2];
#pragma unroll
  for (int c = 0; c < 2; c++)
    bq[c] = *(const bf16x8*)&Qp[(size_t)(q0w + lr) * DH_DIM + c * 32 + lg * 8];

  const f32x4 z4 = {0.f, 0.f, 0.f, 0.f};
  f32x4 Ot[4];
#pragma unroll
  for (int dt = 0; dt < 4; dt++) Ot[dt] = z4;
  float mrow = -1e30f, lrow = 0.f;

  const int st = tid >> 3;        // 0..31: staging row
  const int s8 = tid & 7;         // 16B slot within 128B row
  const int nchunk = qt + 1;
  const int sbase = lane & 48;

  for (int tc = 0; tc < nchunk; ++tc) {
    const int t0 = tc * 64;
    // V -> regs early (latency hide)
    bf16x8 vv0 = *(const bf16x8*)&Vp[(size_t)(t0 + st) * DH_DIM + s8 * 8];
    bf16x8 vv1 = *(const bf16x8*)&Vp[(size_t)(t0 + 32 + st) * DH_DIM + s8 * 8];
    __syncthreads();  // prev chunk's LDS reads done
    // K: global_load_lds with pre-swizzled global source (m173):
    // LDS[t][slot s] holds K[t][8*(s^(t&7))..]; read XORs the same -> identity.
#pragma unroll
    for (int p = 0; p < 2; p++) {
      const int tr = p * 32 + wid * 8 + (lane >> 3);
      const int scol = (lane & 7) ^ (tr & 7);
      GLD16(Kp + (size_t)(t0 + tr) * DH_DIM + scol * 8, &Ks[(p * 32 + wid * 8) * 64]);
    }
    // V^T scatter with swizzle f(d) = (d&7)^((d>>3)&7) (write banks 2-way, read floor)
#pragma unroll
    for (int h2 = 0; h2 < 2; h2++) {
      const bf16x8 vv = h2 ? vv1 : vv0;
      const int t = h2 * 32 + st;
#pragma unroll
      for (int j = 0; j < 8; j++) {
        const int d = s8 * 8 + j;
        const int f = j ^ s8;  // (d&7)^((d>>3)&7)
        Vst[(d * 128 + ((t * 2) ^ (f << 4))) >> 1] = vv[j];
      }
    }
    __syncthreads();

    // S^T = K . Q^T : C rows = t-sub, cols = q
    f32x4 sc[4];
#pragma unroll
    for (int j = 0; j < 4; j++) {
      f32x4 s = z4;
      const int t = j * 16 + lr;
#pragma unroll
      for (int c = 0; c < 2; c++) {
        const int kbyte = t * 128 + (((c * 4 + lg) * 16) ^ ((t & 7) << 4));
        bf16x8 ak = *(const bf16x8*)((const char*)Ks + kbyte);
        s = __builtin_amdgcn_mfma_f32_16x16x32_bf16(ak, bq[c], s, 0, 0, 0);
      }
      sc[j] = s;
    }
    // causal mask (only diagonal chunk needs it; branch is wave-uniform)
    if (tc == nchunk - 1) {
#pragma unroll
      for (int j = 0; j < 4; j++)
#pragma unroll
        for (int r = 0; r < 4; r++) {
          const int tg = t0 + j * 16 + lg * 4 + r;
          if (tg > q0w + lr) sc[j][r] = -1e30f;
        }
    }
    // in-lane softmax for q = lr (16 values/lane, union over 4 lg lanes = 64 t)
    float tmax = sc[0][0];
#pragma unroll
    for (int j = 0; j < 4; j++)
#pragma unroll
      for (int r = 0; r < 4; r++) tmax = fmaxf(tmax, sc[j][r]);
    tmax = fmaxf(tmax, __shfl_xor(tmax, 16, 64));
    tmax = fmaxf(tmax, __shfl_xor(tmax, 32, 64));
    const float mnew = fmaxf(mrow, tmax);
    const float fsc = __builtin_exp2f(mrow - mnew);
    mrow = mnew;
    float tsum = 0.f;
#pragma unroll
    for (int j = 0; j < 4; j++)
#pragma unroll
      for (int r = 0; r < 4; r++) {
        const float p = __builtin_exp2f(sc[j][r] - mnew);
        sc[j][r] = p;
        tsum += p;
      }
    tsum += __shfl_xor(tsum, 16, 64);
    tsum += __shfl_xor(tsum, 32, 64);
    lrow = lrow * fsc + tsum;

    // P -> wave-private LDS [q][t] (b64 stores, swizzle (q&7)<<4), reform A-frags
#pragma unroll
    for (int j = 0; j < 4; j++) {
      bf16x4 w;
#pragma unroll
      for (int r = 0; r < 4; r++) w[r] = (bf16_t)sc[j][r];
      const int pbyte = lr * 128 + ((j * 32 + lg * 8) ^ ((lr & 7) << 4));
      *(bf16x4*)((char*)&Ps[wid][0] + pbyte) = w;
    }
    // rescale O by fsc of q = lg*4+r (fetch from lane holding that q)
    float fr[4];
#pragma unroll
    for (int r = 0; r < 4; r++) fr[r] = __shfl(fsc, sbase | (lg * 4 + r), 64);
#pragma unroll
    for (int dt = 0; dt < 4; dt++)
#pragma unroll
      for (int r = 0; r < 4; r++) Ot[dt][r] *= fr[r];
    // PV: A = P[q][t] (from Ps), B = V^T[d][t] (from Vst)
#pragma unroll
    for (int c = 0; c < 2; c++) {
      const int abyte = lr * 128 + ((c * 64 + lg * 16) ^ ((lr & 7) << 4));
      bf16x8 pa = *(const bf16x8*)((const char*)&Ps[wid][0] + abyte);
#pragma unroll
      for (int dt = 0; dt < 4; dt++) {
        const int d = dt * 16 + lr;
        const int f = (d & 7) ^ ((d >> 3) & 7);
        const int vbyte = d * 128 + (((c * 4 + lg) * 16) ^ (f << 4));
        bf16x8 bv = *(const bf16x8*)((const char*)Vst + vbyte);
        Ot[dt] = __builtin_amdgcn_mfma_f32_16x16x32_bf16(pa, bv, Ot[dt], 0, 0, 0);
      }
    }
  }

  // epilogue: O rows q = lg*4+r, cols d = dt*16+lr; head-concat layout
  float linv[4];
#pragma unroll
  for (int r = 0; r < 4; r++)
    linv[r] = 1.f / __shfl(lrow, sbase | (lg * 4 + r), 64);
  const int b = bh >> 4, h = bh & 15;
#pragma unroll
  for (int r = 0; r < 4; r++) {
    const int s = q0w + lg * 4 + r;
    const size_t base = ((size_t)(b * S_DIM + s)) * E_DIM + h * DH_DIM;
#pragma unroll
    for (int dt = 0; dt < 4; dt++)
      O[base + dt * 16 + lr] = (bf16_t)(Ot[dt][r] * linv[r]);
  }
}

// ---------------- launcher ---------------------------------------------------------
extern "C" void kernel_launch(void* const* d_in, const int* in_sizes, int n_in,
                              void* d_out, int out_size, void* d_ws, size_t ws_size,
                              hipStream_t stream)
{
  const float* x    = (const float*)d_in[0];
  const float* ln1g = (const float*)d_in[1];
  const float* ln1b = (const float*)d_in[2];
  const float* Wq   = (const float*)d_in[3];
  const float* Wk   = (const float*)d_in[4];
  const float* Wv   = (const float*)d_in[5];
  const float* Wo   = (const float*)d_in[6];
  const float* bo   = (const float*)d_in[7];
  const float* ln2g = (const float*)d_in[8];
  const float* ln2b = (const float*)d_in[9];
  const float* W1   = (const float*)d_in[10];
  const float* b1   = (const float*)d_in[11];
  const float* W2   = (const float*)d_in[12];
  const float* b2   = (const float*)d_in[13];

  char* ws = (char*)d_ws;
  bf16_t* WqkvT = (bf16_t*)(ws + 0);          //  6.29 MB  [3072][1024]
  bf16_t* WoT   = (bf16_t*)(ws + 6291456);    //  2.10 MB  [1024][1024]
  bf16_t* W1T   = (bf16_t*)(ws + 8388608);    //  8.39 MB  [4096][1024]
  bf16_t* W2T   = (bf16_t*)(ws + 16777216);   //  8.39 MB  [1024][4096]
  bf16_t* h1    = (bf16_t*)(ws + 25165824);   //  8.39 MB  [4096][1024]
  bf16_t* qb    = (bf16_t*)(ws + 33554432);   //  8.39 MB  [B,H,S,DH]
  bf16_t* kb    = (bf16_t*)(ws + 41943040);   //  8.39 MB
  bf16_t* vb    = (bf16_t*)(ws + 50331648);   //  8.39 MB
  bf16_t* attnb = (bf16_t*)(ws + 58720256);   //  8.39 MB  [4096][1024] (head-concat)
  float*  xmid  = (float* )(ws + 67108864);   // 16.78 MB  [4096][1024] f32
  bf16_t* h2    = (bf16_t*)(ws + 83886080);   //  8.39 MB  -> total 92.3 MB
  bf16_t* ff1   = (bf16_t*)(ws + 25165824);   // 33.55 MB alias over h1/q/k/v (dead by then)

  qkv_transpose<<<dim3(16, 48), 256, 0, stream>>>(Wq, Wk, Wv, WqkvT);
  transpose_cast<<<dim3(16, 16), 256, 0, stream>>>(Wo, WoT, 1024, 1024);
  transpose_cast<<<dim3(64, 16), 256, 0, stream>>>(W1, W1T, 1024, 4096);
  transpose_cast<<<dim3(16, 64), 256, 0, stream>>>(W2, W2T, 4096, 1024);

  ln_kernel<<<4096, 256, 0, stream>>>(x, ln1g, ln1b, h1);
  gemm_kernel<EPI_QKV><<<dim3(32, 24), 256, 0, stream>>>(
      h1, WqkvT, 4096, 3072, 1024, nullptr, nullptr, nullptr, nullptr, qb, kb, vb);
  attn_kernel<<<dim3(32, 32), 256, 0, stream>>>(qb, kb, vb, attnb);
  gemm_kernel<EPI_BIAS_RES><<<dim3(32, 8), 256, 0, stream>>>(
      attnb, WoT, 4096, 1024, 1024, bo, x, xmid, nullptr, nullptr, nullptr, nullptr);
  ln_kernel<<<4096, 256, 0, stream>>>(xmid, ln2g, ln2b, h2);
  gemm_kernel<EPI_BIAS_RELU><<<dim3(32, 32), 256, 0, stream>>>(
      h2, W1T, 4096, 4096, 1024, b1, nullptr, nullptr, ff1, nullptr, nullptr, nullptr);
  gemm_kernel<EPI_BIAS_RES><<<dim3(32, 8), 256, 0, stream>>>(
      ff1, W2T, 4096, 1024, 4096, b2, xmid, (float*)d_out, nullptr, nullptr, nullptr, nullptr);

  (void)in_sizes; (void)n_in; (void)out_size; (void)ws_size;
}

// Round 3
// 294.927 us; speedup vs baseline: 1.5324x; 1.1556x over previous
//
#include <hip/hip_runtime.h>

// TransformerBlock on MI355X: LN1 -> QKV -> causal MHA -> O-proj+res -> LN2 -> FFN+res
// R3: attention KV-split (<=8 chunks/block, flash-decoding combine), K/V double-buffer
// with single barrier per chunk, setprio on MFMA, XCD-aware block swizzle everywhere.

typedef __bf16 bf16_t;
typedef __attribute__((ext_vector_type(8))) __bf16 bf16x8;
typedef __attribute__((ext_vector_type(4))) __bf16 bf16x4;
typedef __attribute__((ext_vector_type(4))) float f32x4;

#define B_DIM 2
#define S_DIM 2048
#define E_DIM 1024
#define H_DIM 16
#define DH_DIM 64

#define GLD16(gp, lp) __builtin_amdgcn_global_load_lds( \
    (const __attribute__((address_space(1))) void*)(gp), \
    (__attribute__((address_space(3))) void*)(lp), 16, 0, 0)

// fold E^-0.5 (=1/32) and log2(e) into Q so softmax can use exp2 directly
#define Q_SCALE 0.0450842120f

// ---------------- LayerNorm: fp32 in -> bf16 out (one block per row) -------------
__global__ __launch_bounds__(256) void ln_kernel(
    const float* __restrict__ x, const float* __restrict__ g,
    const float* __restrict__ bv, bf16_t* __restrict__ out)
{
  const int row = blockIdx.x;
  const int t = threadIdx.x;
  const float* xr = x + (size_t)row * E_DIM;
  float4 v = *(const float4*)&xr[t * 4];
  float s  = v.x + v.y + v.z + v.w;
  float s2 = v.x*v.x + v.y*v.y + v.z*v.z + v.w*v.w;
#pragma unroll
  for (int m = 1; m < 64; m <<= 1) {
    s  += __shfl_xor(s,  m, 64);
    s2 += __shfl_xor(s2, m, 64);
  }
  __shared__ float red[8];
  const int wid = t >> 6, lane = t & 63;
  if (lane == 0) { red[wid] = s; red[4 + wid] = s2; }
  __syncthreads();
  s  = red[0] + red[1] + red[2] + red[3];
  s2 = red[4] + red[5] + red[6] + red[7];
  const float mu  = s * (1.f / E_DIM);
  const float var = s2 * (1.f / E_DIM) - mu * mu;
  const float rs  = rsqrtf(var + 1e-5f);
  float4 gg = *(const float4*)&g[t * 4];
  float4 bb = *(const float4*)&bv[t * 4];
  bf16x4 o;
  o[0] = (bf16_t)((v.x - mu) * rs * gg.x + bb.x);
  o[1] = (bf16_t)((v.y - mu) * rs * gg.y + bb.y);
  o[2] = (bf16_t)((v.z - mu) * rs * gg.z + bb.z);
  o[3] = (bf16_t)((v.w - mu) * rs * gg.w + bb.w);
  *(bf16x4*)&out[(size_t)row * E_DIM + t * 4] = o;
}

// -------- generic transpose+cast: src [R][C] f32 -> dst [C][R] bf16 --------------
__global__ __launch_bounds__(256) void transpose_cast(
    const float* __restrict__ src, bf16_t* __restrict__ dst, int R, int C)
{
  __shared__ float tile[64][65];
  const int c0 = blockIdx.x * 64, r0 = blockIdx.y * 64;
  const int t = threadIdx.x;
  const int rr = t >> 2;
#pragma unroll
  for (int u = 0; u < 4; u++) {
    const int cc = (t & 3) * 4 + u * 16;
    float4 f = *(const float4*)&src[(size_t)(r0 + rr) * C + c0 + cc];
    tile[rr][cc + 0] = f.x; tile[rr][cc + 1] = f.y;
    tile[rr][cc + 2] = f.z; tile[rr][cc + 3] = f.w;
  }
  __syncthreads();
  const int oc = t >> 2;
#pragma unroll
  for (int u = 0; u < 4; u++) {
    const int orr = (t & 3) * 4 + u * 16;
    bf16x4 w;
    w[0] = (bf16_t)tile[orr + 0][oc];
    w[1] = (bf16_t)tile[orr + 1][oc];
    w[2] = (bf16_t)tile[orr + 2][oc];
    w[3] = (bf16_t)tile[orr + 3][oc];
    *(bf16x4*)&dst[(size_t)(c0 + oc) * R + r0 + orr] = w;
  }
}

// -------- QKV weight pack: W{q,k,v}[H][E][DH] f32 -> WqkvT[m*1024+h*64+d][e] bf16 --
__global__ __launch_bounds__(256) void qkv_transpose(
    const float* __restrict__ Wq, const float* __restrict__ Wk,
    const float* __restrict__ Wv, bf16_t* __restrict__ dstT)
{
  const int m = blockIdx.y >> 4, h = blockIdx.y & 15;
  const float* src = (m == 0 ? Wq : (m == 1 ? Wk : Wv)) + (size_t)h * E_DIM * DH_DIM;
  const int e0 = blockIdx.x * 64;
  __shared__ float tile[64][65];
  const int t = threadIdx.x;
  const int rr = t >> 2;
#pragma unroll
  for (int u = 0; u < 4; u++) {
    const int cc = (t & 3) * 4 + u * 16;
    float4 f = *(const float4*)&src[(size_t)(e0 + rr) * DH_DIM + cc];
    tile[rr][cc + 0] = f.x; tile[rr][cc + 1] = f.y;
    tile[rr][cc + 2] = f.z; tile[rr][cc + 3] = f.w;
  }
  __syncthreads();
  const int oc = t >> 2;  // d index 0..63
  const size_t drow = (size_t)(m * 1024 + h * 64 + oc) * E_DIM;
#pragma unroll
  for (int u = 0; u < 4; u++) {
    const int orr = (t & 3) * 4 + u * 16;
    bf16x4 w;
    w[0] = (bf16_t)tile[orr + 0][oc];
    w[1] = (bf16_t)tile[orr + 1][oc];
    w[2] = (bf16_t)tile[orr + 2][oc];
    w[3] = (bf16_t)tile[orr + 3][oc];
    *(bf16x4*)&dstT[drow + e0 + orr] = w;
  }
}

// ---------------- MFMA GEMM: C = A[M,K] * Bt[N,K]^T, templated epilogue ----------
constexpr int EPI_QKV = 0, EPI_BIAS_RES = 1, EPI_BIAS_RELU = 2;

template <int EPI>
__global__ __launch_bounds__(256) void gemm_kernel(
    const bf16_t* __restrict__ A, const bf16_t* __restrict__ Bt,
    int M, int N, int K,
    const float* __restrict__ bias, const float* __restrict__ resid,
    float* __restrict__ outF, bf16_t* __restrict__ outB,
    bf16_t* __restrict__ qo, bf16_t* __restrict__ ko, bf16_t* __restrict__ vo)
{
  __shared__ bf16_t As[128 * 32];
  __shared__ bf16_t Bs[128 * 32];
  // bijective XCD swizzle (m204): nwg % 8 == 0 for all our grids
  const int gx = gridDim.x;
  const int nwg = gx * gridDim.y;
  int id = blockIdx.y * gx + blockIdx.x;
  id = (id & 7) * (nwg >> 3) + (id >> 3);
  const int m0 = (id % gx) * 128, n0 = (id / gx) * 128;

  const int tid = threadIdx.x, lane = tid & 63, wid = tid >> 6;
  const int wr = wid >> 1, wc = wid & 1;
  const int lr = lane & 15, lg = lane >> 4;
  const int rl = lane >> 2, k8 = (lane & 3) * 8;

  const f32x4 z4 = {0.f, 0.f, 0.f, 0.f};
  f32x4 acc[4][4];
#pragma unroll
  for (int i = 0; i < 4; i++)
#pragma unroll
    for (int j = 0; j < 4; j++) acc[i][j] = z4;

  for (int k0 = 0; k0 < K; k0 += 32) {
    __syncthreads();
#pragma unroll
    for (int q = 0; q < 2; q++) {
      const int row = q * 64 + wid * 16 + rl;
      GLD16(A  + (size_t)(m0 + row) * K + k0 + k8, &As[(q * 64 + wid * 16) * 32]);
      GLD16(Bt + (size_t)(n0 + row) * K + k0 + k8, &Bs[(q * 64 + wid * 16) * 32]);
    }
    __syncthreads();
    bf16x8 af[4], bfr[4];
#pragma unroll
    for (int i = 0; i < 4; i++)
      af[i]  = *(const bf16x8*)&As[(wr * 64 + i * 16 + lr) * 32 + lg * 8];
#pragma unroll
    for (int j = 0; j < 4; j++)
      bfr[j] = *(const bf16x8*)&Bs[(wc * 64 + j * 16 + lr) * 32 + lg * 8];
    __builtin_amdgcn_s_setprio(1);
#pragma unroll
    for (int i = 0; i < 4; i++)
#pragma unroll
      for (int j = 0; j < 4; j++)
        acc[i][j] = __builtin_amdgcn_mfma_f32_16x16x32_bf16(af[i], bfr[j], acc[i][j], 0, 0, 0);
    __builtin_amdgcn_s_setprio(0);
  }

#pragma unroll
  for (int i = 0; i < 4; i++) {
#pragma unroll
    for (int j = 0; j < 4; j++) {
#pragma unroll
      for (int r = 0; r < 4; r++) {
        const int m = m0 + wr * 64 + i * 16 + lg * 4 + r;
        const int n = n0 + wc * 64 + j * 16 + lr;
        const float val = acc[i][j][r];
        if constexpr (EPI == EPI_QKV) {
          const int tsel = n >> 10, h = (n >> 6) & 15, d = n & 63;
          const int b = m >> 11, s = m & 2047;
          const size_t idx = ((size_t)((b * H_DIM + h) * S_DIM + s)) * DH_DIM + d;
          if (tsel == 0)      qo[idx] = (bf16_t)(val * Q_SCALE);
          else if (tsel == 1) ko[idx] = (bf16_t)val;
          else                vo[idx] = (bf16_t)val;
        } else if constexpr (EPI == EPI_BIAS_RES) {
          outF[(size_t)m * N + n] = val + bias[n] + resid[(size_t)m * N + n];
        } else {
          const float u = val + bias[n];
          outB[(size_t)m * N + n] = (bf16_t)(u > 0.f ? u : 0.f);
        }
      }
    }
  }
}

// ---------------- causal flash attention, KV-split + double-buffered ---------------
// grid.x = 80 split-blocks per bh (qt 0-7: 1 split; 8-15: 2; 16-23: 3; 24-31: 4,
// each split <= 8 KV chunks of 64). grid.y = B*H. block 256 = 4 waves; wave w owns
// q rows [qt*64+16w, +16). Swapped QK^T (S^T = mfma(K,Q)): lane lr holds q-row lr.
// One barrier per chunk: K double-buffered in LDS (GLD issued after barrier, lands
// during compute), V double-buffered in regs. Splits > 1 emit unnormalized partials.
__global__ __launch_bounds__(256) void attn_kernel(
    const bf16_t* __restrict__ Q, const bf16_t* __restrict__ K,
    const bf16_t* __restrict__ V, bf16_t* __restrict__ O,
    bf16_t* __restrict__ Opart, float* __restrict__ mpart, float* __restrict__ lpart)
{
  __shared__ bf16_t Ks[2][64 * 64];   // [t][d], swizzled: 16B slot ^= (t&7)
  __shared__ bf16_t Vst[2][64 * 64];  // [d][t], swizzled: slot ^= (d&7)^((d>>3)&7)
  __shared__ bf16_t Ps[4][16 * 64];   // per-wave [q][t], swizzled: slot ^= (q&7)

  // XCD swizzle: consecutive new-ids on one XCD share bh's K/V in its L2
  const int nwg = 80 * gridDim.y;
  int id = blockIdx.y * 80 + blockIdx.x;
  id = (id & 7) * (nwg >> 3) + (id >> 3);
  const int bx = id % 80, bh = id / 80;

  int qt, sp, ns;
  if (bx < 8)       { qt = bx;                sp = 0;            ns = 1; }
  else if (bx < 24) { qt = 8 + ((bx - 8) >> 1);  sp = (bx - 8) & 1;  ns = 2; }
  else if (bx < 48) { const int u = bx - 24; const int q3 = u / 3;
                      qt = 16 + q3;           sp = u - q3 * 3;   ns = 3; }
  else              { const int u = bx - 48;  qt = 24 + (u >> 2); sp = u & 3; ns = 4; }
  const int n = qt + 1;
  const int lo = (sp * n) / ns, hi = ((sp + 1) * n) / ns;

  const int q0b = qt * 64;
  const int tid = threadIdx.x;
  const int wid = tid >> 6, lane = tid & 63;
  const int lr = lane & 15, lg = lane >> 4;
  const int q0w = q0b + wid * 16;

  const bf16_t* Qp = Q + (size_t)bh * S_DIM * DH_DIM;
  const bf16_t* Kp = K + (size_t)bh * S_DIM * DH_DIM;
  const bf16_t* Vp = V + (size_t)bh * S_DIM * DH_DIM;

  bf16x8 bq[2];
#pragma unroll
  for (int c = 0; c < 2; c++)
    bq[c] = *(const bf16x8*)&Qp[(size_t)(q0w + lr) * DH_DIM + c * 32 + lg * 8];

  const f32x4 z4 = {0.f, 0.f, 0.f, 0.f};
  f32x4 Ot[4];
#pragma unroll
  for (int dt = 0; dt < 4; dt++) Ot[dt] = z4;
  float mrow = -1e30f, lrow = 0.f;

  const int st = tid >> 3;        // staging row 0..31
  const int s8 = tid & 7;         // 16B slot in 128B row
  const int sbl = lane & 48;
  const int ktr = wid * 8 + (lane >> 3);     // K stage row within 32-half
  const int ksc = (lane & 7);                // K stage 16B col slot

  // prologue: K chunk lo -> Ks[0] (pre-swizzled source), V chunk lo -> regs
  {
    const int t0 = lo * 64;
#pragma unroll
    for (int p = 0; p < 2; p++) {
      const int tr = p * 32 + ktr;
      GLD16(Kp + (size_t)(t0 + tr) * DH_DIM + (ksc ^ (tr & 7)) * 8,
            &Ks[0][(p * 32 + wid * 8) * 64]);
    }
  }
  bf16x8 vc0 = *(const bf16x8*)&Vp[(size_t)(lo * 64 + st) * DH_DIM + s8 * 8];
  bf16x8 vc1 = *(const bf16x8*)&Vp[(size_t)(lo * 64 + 32 + st) * DH_DIM + s8 * 8];
  bf16x8 vn0 = vc0, vn1 = vc1;

  for (int tc = lo; tc < hi; ++tc) {
    const int cur = (tc - lo) & 1;
    // scatter V(tc) regs -> Vst[cur] (prev compute on [cur^1]; [cur] free since
    // all waves passed barrier(tc-1) which followed compute(tc-2))
#pragma unroll
    for (int h2 = 0; h2 < 2; h2++) {
      const bf16x8 vv = h2 ? vc1 : vc0;
      const int t = h2 * 32 + st;
#pragma unroll
      for (int j = 0; j < 8; j++) {
        const int d = s8 * 8 + j;
        const int f = j ^ s8;
        Vst[cur][(d * 128 + ((t * 2) ^ (f << 4))) >> 1] = vv[j];
      }
    }
    __syncthreads();  // drains K(tc) GLD + V scatter; all waves done with [cur^1]
    if (tc + 1 < hi) {  // prefetch chunk tc+1 during compute (lands by next barrier)
      const int t1 = (tc + 1) * 64;
#pragma unroll
      for (int p = 0; p < 2; p++) {
        const int tr = p * 32 + ktr;
        GLD16(Kp + (size_t)(t1 + tr) * DH_DIM + (ksc ^ (tr & 7)) * 8,
              &Ks[cur ^ 1][(p * 32 + wid * 8) * 64]);
      }
      vn0 = *(const bf16x8*)&Vp[(size_t)(t1 + st) * DH_DIM + s8 * 8];
      vn1 = *(const bf16x8*)&Vp[(size_t)(t1 + 32 + st) * DH_DIM + s8 * 8];
    }

    const int t0 = tc * 64;
    // S^T = K . Q^T : lane (lr,lg) cols q=lr, rows t-sub
    f32x4 sc[4];
    __builtin_amdgcn_s_setprio(1);
#pragma unroll
    for (int j = 0; j < 4; j++) {
      f32x4 s = z4;
      const int t = j * 16 + lr;
#pragma unroll
      for (int c = 0; c < 2; c++) {
        const int kbyte = t * 128 + (((c * 4 + lg) * 16) ^ ((t & 7) << 4));
        bf16x8 ak = *(const bf16x8*)((const char*)&Ks[cur][0] + kbyte);
        s = __builtin_amdgcn_mfma_f32_16x16x32_bf16(ak, bq[c], s, 0, 0, 0);
      }
      sc[j] = s;
    }
    __builtin_amdgcn_s_setprio(0);
    if (tc == qt) {  // diagonal chunk: causal mask
#pragma unroll
      for (int j = 0; j < 4; j++)
#pragma unroll
        for (int r = 0; r < 4; r++) {
          const int tg = t0 + j * 16 + lg * 4 + r;
          if (tg > q0w + lr) sc[j][r] = -1e30f;
        }
    }
    // in-lane softmax for q = lr
    float tmax = sc[0][0];
#pragma unroll
    for (int j = 0; j < 4; j++)
#pragma unroll
      for (int r = 0; r < 4; r++) tmax = fmaxf(tmax, sc[j][r]);
    tmax = fmaxf(tmax, __shfl_xor(tmax, 16, 64));
    tmax = fmaxf(tmax, __shfl_xor(tmax, 32, 64));
    const float mnew = fmaxf(mrow, tmax);
    const float fsc = __builtin_exp2f(mrow - mnew);
    mrow = mnew;
    float tsum = 0.f;
#pragma unroll
    for (int j = 0; j < 4; j++)
#pragma unroll
      for (int r = 0; r < 4; r++) {
        const float p = __builtin_exp2f(sc[j][r] - mnew);
        sc[j][r] = p;
        tsum += p;
      }
    tsum += __shfl_xor(tsum, 16, 64);
    tsum += __shfl_xor(tsum, 32, 64);
    lrow = lrow * fsc + tsum;

    // P -> wave-private LDS, reform as A-fragments
#pragma unroll
    for (int j = 0; j < 4; j++) {
      bf16x4 w;
#pragma unroll
      for (int r = 0; r < 4; r++) w[r] = (bf16_t)sc[j][r];
      const int pbyte = lr * 128 + ((j * 32 + lg * 8) ^ ((lr & 7) << 4));
      *(bf16x4*)((char*)&Ps[wid][0] + pbyte) = w;
    }
    float fr[4];
#pragma unroll
    for (int r = 0; r < 4; r++) fr[r] = __shfl(fsc, sbl | (lg * 4 + r), 64);
#pragma unroll
    for (int dt = 0; dt < 4; dt++)
#pragma unroll
      for (int r = 0; r < 4; r++) Ot[dt][r] *= fr[r];
    __builtin_amdgcn_s_setprio(1);
#pragma unroll
    for (int c = 0; c < 2; c++) {
      const int abyte = lr * 128 + ((c * 64 + lg * 16) ^ ((lr & 7) << 4));
      bf16x8 pa = *(const bf16x8*)((const char*)&Ps[wid][0] + abyte);
#pragma unroll
      for (int dt = 0; dt < 4; dt++) {
        const int d = dt * 16 + lr;
        const int f = (d & 7) ^ ((d >> 3) & 7);
        const int vbyte = d * 128 + (((c * 4 + lg) * 16) ^ (f << 4));
        bf16x8 bv = *(const bf16x8*)((const char*)&Vst[cur][0] + vbyte);
        Ot[dt] = __builtin_amdgcn_mfma_f32_16x16x32_bf16(pa, bv, Ot[dt], 0, 0, 0);
      }
    }
    __builtin_amdgcn_s_setprio(0);
    vc0 = vn0; vc1 = vn1;
  }

  if (ns == 1) {
    // normalized direct write (head-concat layout)
    float linv[4];
#pragma unroll
    for (int r = 0; r < 4; r++)
      linv[r] = 1.f / __shfl(lrow, sbl | (lg * 4 + r), 64);
    const int b = bh >> 4, h = bh & 15;
#pragma unroll
    for (int r = 0; r < 4; r++) {
      const int s = q0w + lg * 4 + r;
      const size_t base = ((size_t)(b * S_DIM + s)) * E_DIM + h * DH_DIM;
#pragma unroll
      for (int dt = 0; dt < 4; dt++)
        O[base + dt * 16 + lr] = (bf16_t)(Ot[dt][r] * linv[r]);
    }
  } else {
    // unnormalized partial (relative to this split's running max)
    const int sbase = (qt < 16) ? 8 + 2 * (qt - 8)
                     : (qt < 24) ? 24 + 3 * (qt - 16) : 48 + 4 * (qt - 24);
    const int slot = bh * 80 + sbase + sp;
    bf16_t* Ob = Opart + (size_t)slot * 64 * 64;
#pragma unroll
    for (int r = 0; r < 4; r++)
#pragma unroll
      for (int dt = 0; dt < 4; dt++)
        Ob[(wid * 16 + lg * 4 + r) * 64 + dt * 16 + lr] = (bf16_t)Ot[dt][r];
    if (lg == 0) {
      mpart[slot * 64 + wid * 16 + lr] = mrow;
      lpart[slot * 64 + wid * 16 + lr] = lrow;
    }
  }
}

// ---------------- combine partials for qt >= 8 -------------------------------------
__global__ __launch_bounds__(256) void attn_combine(
    const bf16_t* __restrict__ Opart, const float* __restrict__ mpart,
    const float* __restrict__ lpart, bf16_t* __restrict__ O)
{
  const int qt = 8 + blockIdx.x;      // 8..31
  const int bh = blockIdx.y;
  const int ns = (qt < 16) ? 2 : (qt < 24) ? 3 : 4;
  const int sbase = (qt < 16) ? 8 + 2 * (qt - 8)
                   : (qt < 24) ? 24 + 3 * (qt - 16) : 48 + 4 * (qt - 24);
  const int slot0 = bh * 80 + sbase;
  const int tid = threadIdx.x;
  const int q = tid >> 2, d0 = (tid & 3) * 16;

  float M = -1e30f;
  for (int s = 0; s < ns; s++) M = fmaxf(M, mpart[(slot0 + s) * 64 + q]);
  float L = 0.f;
  float acc[16];
#pragma unroll
  for (int j = 0; j < 16; j++) acc[j] = 0.f;
  for (int s = 0; s < ns; s++) {
    const float w = __builtin_exp2f(mpart[(slot0 + s) * 64 + q] - M);
    L += w * lpart[(slot0 + s) * 64 + q];
    const bf16_t* Ob = Opart + ((size_t)(slot0 + s) * 64 + q) * 64 + d0;
    bf16x8 o0 = *(const bf16x8*)Ob;
    bf16x8 o1 = *(const bf16x8*)(Ob + 8);
#pragma unroll
    for (int j = 0; j < 8; j++) { acc[j] += w * (float)o0[j]; acc[8 + j] += w * (float)o1[j]; }
  }
  const float inv = 1.f / L;
  const int b = bh >> 4, h = bh & 15;
  const int srow = qt * 64 + q;
  bf16_t* out = O + ((size_t)(b * S_DIM + srow)) * E_DIM + h * DH_DIM + d0;
  bf16x8 w0, w1;
#pragma unroll
  for (int j = 0; j < 8; j++) { w0[j] = (bf16_t)(acc[j] * inv); w1[j] = (bf16_t)(acc[8 + j] * inv); }
  *(bf16x8*)out = w0;
  *(bf16x8*)(out + 8) = w1;
}

// ---------------- launcher ---------------------------------------------------------
extern "C" void kernel_launch(void* const* d_in, const int* in_sizes, int n_in,
                              void* d_out, int out_size, void* d_ws, size_t ws_size,
                              hipStream_t stream)
{
  const float* x    = (const float*)d_in[0];
  const float* ln1g = (const float*)d_in[1];
  const float* ln1b = (const float*)d_in[2];
  const float* Wq   = (const float*)d_in[3];
  const float* Wk   = (const float*)d_in[4];
  const float* Wv   = (const float*)d_in[5];
  const float* Wo   = (const float*)d_in[6];
  const float* bo   = (const float*)d_in[7];
  const float* ln2g = (const float*)d_in[8];
  const float* ln2b = (const float*)d_in[9];
  const float* W1   = (const float*)d_in[10];
  const float* b1   = (const float*)d_in[11];
  const float* W2   = (const float*)d_in[12];
  const float* b2   = (const float*)d_in[13];

  char* ws = (char*)d_ws;
  bf16_t* WqkvT = (bf16_t*)(ws + 0);          //  6.29 MB  [3072][1024]
  bf16_t* WoT   = (bf16_t*)(ws + 6291456);    //  2.10 MB  [1024][1024]
  bf16_t* W1T   = (bf16_t*)(ws + 8388608);    //  8.39 MB  [4096][1024]
  bf16_t* W2T   = (bf16_t*)(ws + 16777216);   //  8.39 MB  [1024][4096]
  bf16_t* h1    = (bf16_t*)(ws + 25165824);   //  8.39 MB  [4096][1024] (dead after QKV)
  bf16_t* qb    = (bf16_t*)(ws + 33554432);   //  8.39 MB  [B,H,S,DH]
  bf16_t* kb    = (bf16_t*)(ws + 41943040);   //  8.39 MB
  bf16_t* vb    = (bf16_t*)(ws + 50331648);   //  8.39 MB
  bf16_t* attnb = (bf16_t*)(ws + 58720256);   //  8.39 MB  [4096][1024] (head-concat)
  float*  xmid  = (float* )(ws + 67108864);   // 16.78 MB  [4096][1024] f32
  bf16_t* h2    = (bf16_t*)(ws + 83886080);   //  8.39 MB
  bf16_t* ff1   = (bf16_t*)(ws + 25165824);   // 33.55 MB alias over h1/q/k/v (dead by FFN)
  // attention partials (live only between attn and combine; clobbered later by xmid/ff1)
  bf16_t* Opart = (bf16_t*)(ws + 67108864);   // 20.97 MB  [2560][64][64] bf16 (over xmid/h2)
  float*  mpart = (float* )(ws + 25165824);   //  0.66 MB  (over h1, dead)
  float*  lpart = (float* )(ws + 25821184);   //  0.66 MB

  qkv_transpose<<<dim3(16, 48), 256, 0, stream>>>(Wq, Wk, Wv, WqkvT);
  transpose_cast<<<dim3(16, 16), 256, 0, stream>>>(Wo, WoT, 1024, 1024);
  transpose_cast<<<dim3(64, 16), 256, 0, stream>>>(W1, W1T, 1024, 4096);
  transpose_cast<<<dim3(16, 64), 256, 0, stream>>>(W2, W2T, 4096, 1024);

  ln_kernel<<<4096, 256, 0, stream>>>(x, ln1g, ln1b, h1);
  gemm_kernel<EPI_QKV><<<dim3(32, 24), 256, 0, stream>>>(
      h1, WqkvT, 4096, 3072, 1024, nullptr, nullptr, nullptr, nullptr, qb, kb, vb);
  attn_kernel<<<dim3(80, 32), 256, 0, stream>>>(qb, kb, vb, attnb, Opart, mpart, lpart);
  attn_combine<<<dim3(24, 32), 256, 0, stream>>>(Opart, mpart, lpart, attnb);
  gemm_kernel<EPI_BIAS_RES><<<dim3(32, 8), 256, 0, stream>>>(
      attnb, WoT, 4096, 1024, 1024, bo, x, xmid, nullptr, nullptr, nullptr, nullptr);
  ln_kernel<<<4096, 256, 0, stream>>>(xmid, ln2g, ln2b, h2);
  gemm_kernel<EPI_BIAS_RELU><<<dim3(32, 32), 256, 0, stream>>>(
      h2, W1T, 4096, 4096, 1024, b1, nullptr, nullptr, ff1, nullptr, nullptr, nullptr);
  gemm_kernel<EPI_BIAS_RES><<<dim3(32, 8), 256, 0, stream>>>(
      ff1, W2T, 4096, 1024, 4096, b2, xmid, (float*)d_out, nullptr, nullptr, nullptr, nullptr);

  (void)in_sizes; (void)n_in; (void)out_size; (void)ws_size;
}

// Round 4
// 284.938 us; speedup vs baseline: 1.5861x; 1.0351x over previous
//
#include <hip/hip_runtime.h>

// TransformerBlock on MI355X: LN1 -> QKV -> causal MHA -> O-proj+res -> LN2 -> FFN+res
// R4: GEMM double-buffered (1 barrier/iter, prefetch overlaps MFMA); split-K for the
// two N=1024 GEMMs (O-proj x2, FFN2 x4) with fused combine kernels (reduce2_ln fuses
// O-combine+bias+residual+LN2; reduce4 fuses FFN2-combine+bias+residual->d_out).

typedef __bf16 bf16_t;
typedef __attribute__((ext_vector_type(8))) __bf16 bf16x8;
typedef __attribute__((ext_vector_type(4))) __bf16 bf16x4;
typedef __attribute__((ext_vector_type(4))) float f32x4;

#define B_DIM 2
#define S_DIM 2048
#define E_DIM 1024
#define H_DIM 16
#define DH_DIM 64

#define GLD16(gp, lp) __builtin_amdgcn_global_load_lds( \
    (const __attribute__((address_space(1))) void*)(gp), \
    (__attribute__((address_space(3))) void*)(lp), 16, 0, 0)

// fold E^-0.5 (=1/32) and log2(e) into Q so softmax can use exp2 directly
#define Q_SCALE 0.0450842120f

// ---------------- LayerNorm: fp32 in -> bf16 out (one block per row) -------------
__global__ __launch_bounds__(256) void ln_kernel(
    const float* __restrict__ x, const float* __restrict__ g,
    const float* __restrict__ bv, bf16_t* __restrict__ out)
{
  const int row = blockIdx.x;
  const int t = threadIdx.x;
  const float* xr = x + (size_t)row * E_DIM;
  float4 v = *(const float4*)&xr[t * 4];
  float s  = v.x + v.y + v.z + v.w;
  float s2 = v.x*v.x + v.y*v.y + v.z*v.z + v.w*v.w;
#pragma unroll
  for (int m = 1; m < 64; m <<= 1) {
    s  += __shfl_xor(s,  m, 64);
    s2 += __shfl_xor(s2, m, 64);
  }
  __shared__ float red[8];
  const int wid = t >> 6, lane = t & 63;
  if (lane == 0) { red[wid] = s; red[4 + wid] = s2; }
  __syncthreads();
  s  = red[0] + red[1] + red[2] + red[3];
  s2 = red[4] + red[5] + red[6] + red[7];
  const float mu  = s * (1.f / E_DIM);
  const float var = s2 * (1.f / E_DIM) - mu * mu;
  const float rs  = rsqrtf(var + 1e-5f);
  float4 gg = *(const float4*)&g[t * 4];
  float4 bb = *(const float4*)&bv[t * 4];
  bf16x4 o;
  o[0] = (bf16_t)((v.x - mu) * rs * gg.x + bb.x);
  o[1] = (bf16_t)((v.y - mu) * rs * gg.y + bb.y);
  o[2] = (bf16_t)((v.z - mu) * rs * gg.z + bb.z);
  o[3] = (bf16_t)((v.w - mu) * rs * gg.w + bb.w);
  *(bf16x4*)&out[(size_t)row * E_DIM + t * 4] = o;
}

// ---- O-proj split-K combine + bias + residual -> xmid(f32), then LN2 -> h2(bf16) --
__global__ __launch_bounds__(256) void reduce2_ln(
    const float* __restrict__ p, const float* __restrict__ bo,
    const float* __restrict__ x, const float* __restrict__ g,
    const float* __restrict__ bv, float* __restrict__ xmid, bf16_t* __restrict__ h2)
{
  const int row = blockIdx.x;
  const int t = threadIdx.x;
  const size_t off = (size_t)row * E_DIM + t * 4;
  float4 a  = *(const float4*)&p[off];
  float4 b4 = *(const float4*)&p[(size_t)4096 * E_DIM + off];
  float4 xr = *(const float4*)&x[off];
  float4 bo4 = *(const float4*)&bo[t * 4];
  float4 v;
  v.x = a.x + b4.x + xr.x + bo4.x;
  v.y = a.y + b4.y + xr.y + bo4.y;
  v.z = a.z + b4.z + xr.z + bo4.z;
  v.w = a.w + b4.w + xr.w + bo4.w;
  *(float4*)&xmid[off] = v;
  float s  = v.x + v.y + v.z + v.w;
  float s2 = v.x*v.x + v.y*v.y + v.z*v.z + v.w*v.w;
#pragma unroll
  for (int m = 1; m < 64; m <<= 1) {
    s  += __shfl_xor(s,  m, 64);
    s2 += __shfl_xor(s2, m, 64);
  }
  __shared__ float red[8];
  const int wid = t >> 6, lane = t & 63;
  if (lane == 0) { red[wid] = s; red[4 + wid] = s2; }
  __syncthreads();
  s  = red[0] + red[1] + red[2] + red[3];
  s2 = red[4] + red[5] + red[6] + red[7];
  const float mu  = s * (1.f / E_DIM);
  const float var = s2 * (1.f / E_DIM) - mu * mu;
  const float rs  = rsqrtf(var + 1e-5f);
  float4 gg = *(const float4*)&g[t * 4];
  float4 bb = *(const float4*)&bv[t * 4];
  bf16x4 o;
  o[0] = (bf16_t)((v.x - mu) * rs * gg.x + bb.x);
  o[1] = (bf16_t)((v.y - mu) * rs * gg.y + bb.y);
  o[2] = (bf16_t)((v.z - mu) * rs * gg.z + bb.z);
  o[3] = (bf16_t)((v.w - mu) * rs * gg.w + bb.w);
  *(bf16x4*)&h2[off] = o;
}

// ---- FFN2 split-K combine (4 bf16 partials) + bias + residual -> d_out (f32) -----
__global__ __launch_bounds__(256) void reduce4(
    const bf16_t* __restrict__ p0, const bf16_t* __restrict__ p1,
    const bf16_t* __restrict__ p2, const bf16_t* __restrict__ p3,
    const float* __restrict__ b2, const float* __restrict__ xm,
    float* __restrict__ out)
{
  const int row = blockIdx.x;
  const int t = threadIdx.x;
  const size_t off = (size_t)row * E_DIM + t * 4;
  bf16x4 a0 = *(const bf16x4*)&p0[off];
  bf16x4 a1 = *(const bf16x4*)&p1[off];
  bf16x4 a2 = *(const bf16x4*)&p2[off];
  bf16x4 a3 = *(const bf16x4*)&p3[off];
  float4 xr = *(const float4*)&xm[off];
  float4 bb = *(const float4*)&b2[t * 4];
  float4 o;
  o.x = (float)a0[0] + (float)a1[0] + (float)a2[0] + (float)a3[0] + xr.x + bb.x;
  o.y = (float)a0[1] + (float)a1[1] + (float)a2[1] + (float)a3[1] + xr.y + bb.y;
  o.z = (float)a0[2] + (float)a1[2] + (float)a2[2] + (float)a3[2] + xr.z + bb.z;
  o.w = (float)a0[3] + (float)a1[3] + (float)a2[3] + (float)a3[3] + xr.w + bb.w;
  *(float4*)&out[off] = o;
}

// -------- generic transpose+cast: src [R][C] f32 -> dst [C][R] bf16 --------------
__global__ __launch_bounds__(256) void transpose_cast(
    const float* __restrict__ src, bf16_t* __restrict__ dst, int R, int C)
{
  __shared__ float tile[64][65];
  const int c0 = blockIdx.x * 64, r0 = blockIdx.y * 64;
  const int t = threadIdx.x;
  const int rr = t >> 2;
#pragma unroll
  for (int u = 0; u < 4; u++) {
    const int cc = (t & 3) * 4 + u * 16;
    float4 f = *(const float4*)&src[(size_t)(r0 + rr) * C + c0 + cc];
    tile[rr][cc + 0] = f.x; tile[rr][cc + 1] = f.y;
    tile[rr][cc + 2] = f.z; tile[rr][cc + 3] = f.w;
  }
  __syncthreads();
  const int oc = t >> 2;
#pragma unroll
  for (int u = 0; u < 4; u++) {
    const int orr = (t & 3) * 4 + u * 16;
    bf16x4 w;
    w[0] = (bf16_t)tile[orr + 0][oc];
    w[1] = (bf16_t)tile[orr + 1][oc];
    w[2] = (bf16_t)tile[orr + 2][oc];
    w[3] = (bf16_t)tile[orr + 3][oc];
    *(bf16x4*)&dst[(size_t)(c0 + oc) * R + r0 + orr] = w;
  }
}

// -------- QKV weight pack: W{q,k,v}[H][E][DH] f32 -> WqkvT[m*1024+h*64+d][e] bf16 --
__global__ __launch_bounds__(256) void qkv_transpose(
    const float* __restrict__ Wq, const float* __restrict__ Wk,
    const float* __restrict__ Wv, bf16_t* __restrict__ dstT)
{
  const int m = blockIdx.y >> 4, h = blockIdx.y & 15;
  const float* src = (m == 0 ? Wq : (m == 1 ? Wk : Wv)) + (size_t)h * E_DIM * DH_DIM;
  const int e0 = blockIdx.x * 64;
  __shared__ float tile[64][65];
  const int t = threadIdx.x;
  const int rr = t >> 2;
#pragma unroll
  for (int u = 0; u < 4; u++) {
    const int cc = (t & 3) * 4 + u * 16;
    float4 f = *(const float4*)&src[(size_t)(e0 + rr) * DH_DIM + cc];
    tile[rr][cc + 0] = f.x; tile[rr][cc + 1] = f.y;
    tile[rr][cc + 2] = f.z; tile[rr][cc + 3] = f.w;
  }
  __syncthreads();
  const int oc = t >> 2;  // d index 0..63
  const size_t drow = (size_t)(m * 1024 + h * 64 + oc) * E_DIM;
#pragma unroll
  for (int u = 0; u < 4; u++) {
    const int orr = (t & 3) * 4 + u * 16;
    bf16x4 w;
    w[0] = (bf16_t)tile[orr + 0][oc];
    w[1] = (bf16_t)tile[orr + 1][oc];
    w[2] = (bf16_t)tile[orr + 2][oc];
    w[3] = (bf16_t)tile[orr + 3][oc];
    *(bf16x4*)&dstT[drow + e0 + orr] = w;
  }
}

// ---------------- MFMA GEMM: C = A[M,Kst](cols sp*Klen..) * Bt^T, dbuf pipeline ----
constexpr int EPI_QKV = 0, EPI_BIAS_RELU = 2, EPI_PART_F32 = 3, EPI_PART_B16 = 4;

template <int EPI>
__global__ __launch_bounds__(256) void gemm_kernel(
    const bf16_t* __restrict__ A, const bf16_t* __restrict__ Bt,
    int M, int N, int Kst, int Klen,
    const float* __restrict__ bias, const float* __restrict__ resid,
    float* __restrict__ outF, bf16_t* __restrict__ outB,
    bf16_t* __restrict__ qo, bf16_t* __restrict__ ko, bf16_t* __restrict__ vo)
{
  __shared__ bf16_t As[2][128 * 32];
  __shared__ bf16_t Bs[2][128 * 32];
  // bijective XCD swizzle within each z-slice (nwg % 8 == 0 for all our grids)
  const int gx = gridDim.x;
  const int nwg = gx * gridDim.y;
  int id = blockIdx.y * gx + blockIdx.x;
  id = (id & 7) * (nwg >> 3) + (id >> 3);
  const int m0 = (id % gx) * 128, n0 = (id / gx) * 128;
  const int sp = blockIdx.z;
  A  += (size_t)sp * Klen;
  Bt += (size_t)sp * Klen;

  const int tid = threadIdx.x, lane = tid & 63, wid = tid >> 6;
  const int wr = wid >> 1, wc = wid & 1;
  const int lr = lane & 15, lg = lane >> 4;
  const int rl = lane >> 2, k8 = (lane & 3) * 8;

  auto stage = [&](int buf, int k0) {
#pragma unroll
    for (int q = 0; q < 2; q++) {
      const int row = q * 64 + wid * 16 + rl;
      GLD16(A  + (size_t)(m0 + row) * Kst + k0 + k8, &As[buf][(q * 64 + wid * 16) * 32]);
      GLD16(Bt + (size_t)(n0 + row) * Kst + k0 + k8, &Bs[buf][(q * 64 + wid * 16) * 32]);
    }
  };

  const f32x4 z4 = {0.f, 0.f, 0.f, 0.f};
  f32x4 acc[4][4];
#pragma unroll
  for (int i = 0; i < 4; i++)
#pragma unroll
    for (int j = 0; j < 4; j++) acc[i][j] = z4;

  const int nt = Klen / 32;
  stage(0, 0);
  for (int it = 0; it < nt; ++it) {
    const int cur = it & 1;
    __syncthreads();  // drains this wave's GLD(it) [compiler vmcnt(0)] + joins waves
    if (it + 1 < nt) stage(cur ^ 1, (it + 1) * 32);  // flies under the MFMAs below
    bf16x8 af[4], bfr[4];
#pragma unroll
    for (int i = 0; i < 4; i++)
      af[i]  = *(const bf16x8*)&As[cur][(wr * 64 + i * 16 + lr) * 32 + lg * 8];
#pragma unroll
    for (int j = 0; j < 4; j++)
      bfr[j] = *(const bf16x8*)&Bs[cur][(wc * 64 + j * 16 + lr) * 32 + lg * 8];
    __builtin_amdgcn_s_setprio(1);
#pragma unroll
    for (int i = 0; i < 4; i++)
#pragma unroll
      for (int j = 0; j < 4; j++)
        acc[i][j] = __builtin_amdgcn_mfma_f32_16x16x32_bf16(af[i], bfr[j], acc[i][j], 0, 0, 0);
    __builtin_amdgcn_s_setprio(0);
  }

#pragma unroll
  for (int i = 0; i < 4; i++) {
#pragma unroll
    for (int j = 0; j < 4; j++) {
#pragma unroll
      for (int r = 0; r < 4; r++) {
        const int m = m0 + wr * 64 + i * 16 + lg * 4 + r;
        const int n = n0 + wc * 64 + j * 16 + lr;
        const float val = acc[i][j][r];
        if constexpr (EPI == EPI_QKV) {
          const int tsel = n >> 10, h = (n >> 6) & 15, d = n & 63;
          const int b = m >> 11, s = m & 2047;
          const size_t idx = ((size_t)((b * H_DIM + h) * S_DIM + s)) * DH_DIM + d;
          if (tsel == 0)      qo[idx] = (bf16_t)(val * Q_SCALE);
          else if (tsel == 1) ko[idx] = (bf16_t)val;
          else                vo[idx] = (bf16_t)val;
        } else if constexpr (EPI == EPI_BIAS_RELU) {
          const float u = val + bias[n];
          outB[(size_t)m * N + n] = (bf16_t)(u > 0.f ? u : 0.f);
        } else if constexpr (EPI == EPI_PART_F32) {
          outF[(size_t)sp * M * N + (size_t)m * N + n] = val;
        } else {  // EPI_PART_B16: per-split bf16 partial buffers
          bf16_t* o = sp == 0 ? outB : sp == 1 ? qo : sp == 2 ? ko : vo;
          o[(size_t)m * N + n] = (bf16_t)val;
        }
      }
    }
  }
}

// ---------------- causal flash attention, KV-split + double-buffered ---------------
// grid.x = 80 split-blocks per bh (qt 0-7: 1 split; 8-15: 2; 16-23: 3; 24-31: 4,
// each split <= 8 KV chunks of 64). grid.y = B*H. block 256 = 4 waves; wave w owns
// q rows [qt*64+16w, +16). Swapped QK^T (S^T = mfma(K,Q)): lane lr holds q-row lr.
__global__ __launch_bounds__(256) void attn_kernel(
    const bf16_t* __restrict__ Q, const bf16_t* __restrict__ K,
    const bf16_t* __restrict__ V, bf16_t* __restrict__ O,
    bf16_t* __restrict__ Opart, float* __restrict__ mpart, float* __restrict__ lpart)
{
  __shared__ bf16_t Ks[2][64 * 64];   // [t][d], swizzled: 16B slot ^= (t&7)
  __shared__ bf16_t Vst[2][64 * 64];  // [d][t], swizzled: slot ^= (d&7)^((d>>3)&7)
  __shared__ bf16_t Ps[4][16 * 64];   // per-wave [q][t], swizzled: slot ^= (q&7)

  const int nwg = 80 * gridDim.y;
  int id = blockIdx.y * 80 + blockIdx.x;
  id = (id & 7) * (nwg >> 3) + (id >> 3);
  const int bx = id % 80, bh = id / 80;

  int qt, sp, ns;
  if (bx < 8)       { qt = bx;                sp = 0;            ns = 1; }
  else if (bx < 24) { qt = 8 + ((bx - 8) >> 1);  sp = (bx - 8) & 1;  ns = 2; }
  else if (bx < 48) { const int u = bx - 24; const int q3 = u / 3;
                      qt = 16 + q3;           sp = u - q3 * 3;   ns = 3; }
  else              { const int u = bx - 48;  qt = 24 + (u >> 2); sp = u & 3; ns = 4; }
  const int n = qt + 1;
  const int lo = (sp * n) / ns, hi = ((sp + 1) * n) / ns;

  const int q0b = qt * 64;
  const int tid = threadIdx.x;
  const int wid = tid >> 6, lane = tid & 63;
  const int lr = lane & 15, lg = lane >> 4;
  const int q0w = q0b + wid * 16;

  const bf16_t* Qp = Q + (size_t)bh * S_DIM * DH_DIM;
  const bf16_t* Kp = K + (size_t)bh * S_DIM * DH_DIM;
  const bf16_t* Vp = V + (size_t)bh * S_DIM * DH_DIM;

  bf16x8 bq[2];
#pragma unroll
  for (int c = 0; c < 2; c++)
    bq[c] = *(const bf16x8*)&Qp[(size_t)(q0w + lr) * DH_DIM + c * 32 + lg * 8];

  const f32x4 z4 = {0.f, 0.f, 0.f, 0.f};
  f32x4 Ot[4];
#pragma unroll
  for (int dt = 0; dt < 4; dt++) Ot[dt] = z4;
  float mrow = -1e30f, lrow = 0.f;

  const int st = tid >> 3;        // staging row 0..31
  const int s8 = tid & 7;         // 16B slot in 128B row
  const int sbl = lane & 48;
  const int ktr = wid * 8 + (lane >> 3);
  const int ksc = (lane & 7);

  {
    const int t0 = lo * 64;
#pragma unroll
    for (int p = 0; p < 2; p++) {
      const int tr = p * 32 + ktr;
      GLD16(Kp + (size_t)(t0 + tr) * DH_DIM + (ksc ^ (tr & 7)) * 8,
            &Ks[0][(p * 32 + wid * 8) * 64]);
    }
  }
  bf16x8 vc0 = *(const bf16x8*)&Vp[(size_t)(lo * 64 + st) * DH_DIM + s8 * 8];
  bf16x8 vc1 = *(const bf16x8*)&Vp[(size_t)(lo * 64 + 32 + st) * DH_DIM + s8 * 8];
  bf16x8 vn0 = vc0, vn1 = vc1;

  for (int tc = lo; tc < hi; ++tc) {
    const int cur = (tc - lo) & 1;
#pragma unroll
    for (int h2 = 0; h2 < 2; h2++) {
      const bf16x8 vv = h2 ? vc1 : vc0;
      const int t = h2 * 32 + st;
#pragma unroll
      for (int j = 0; j < 8; j++) {
        const int d = s8 * 8 + j;
        const int f = j ^ s8;
        Vst[cur][(d * 128 + ((t * 2) ^ (f << 4))) >> 1] = vv[j];
      }
    }
    __syncthreads();
    if (tc + 1 < hi) {
      const int t1 = (tc + 1) * 64;
#pragma unroll
      for (int p = 0; p < 2; p++) {
        const int tr = p * 32 + ktr;
        GLD16(Kp + (size_t)(t1 + tr) * DH_DIM + (ksc ^ (tr & 7)) * 8,
              &Ks[cur ^ 1][(p * 32 + wid * 8) * 64]);
      }
      vn0 = *(const bf16x8*)&Vp[(size_t)(t1 + st) * DH_DIM + s8 * 8];
      vn1 = *(const bf16x8*)&Vp[(size_t)(t1 + 32 + st) * DH_DIM + s8 * 8];
    }

    const int t0 = tc * 64;
    f32x4 sc[4];
    __builtin_amdgcn_s_setprio(1);
#pragma unroll
    for (int j = 0; j < 4; j++) {
      f32x4 s = z4;
      const int t = j * 16 + lr;
#pragma unroll
      for (int c = 0; c < 2; c++) {
        const int kbyte = t * 128 + (((c * 4 + lg) * 16) ^ ((t & 7) << 4));
        bf16x8 ak = *(const bf16x8*)((const char*)&Ks[cur][0] + kbyte);
        s = __builtin_amdgcn_mfma_f32_16x16x32_bf16(ak, bq[c], s, 0, 0, 0);
      }
      sc[j] = s;
    }
    __builtin_amdgcn_s_setprio(0);
    if (tc == qt) {
#pragma unroll
      for (int j = 0; j < 4; j++)
#pragma unroll
        for (int r = 0; r < 4; r++) {
          const int tg = t0 + j * 16 + lg * 4 + r;
          if (tg > q0w + lr) sc[j][r] = -1e30f;
        }
    }
    float tmax = sc[0][0];
#pragma unroll
    for (int j = 0; j < 4; j++)
#pragma unroll
      for (int r = 0; r < 4; r++) tmax = fmaxf(tmax, sc[j][r]);
    tmax = fmaxf(tmax, __shfl_xor(tmax, 16, 64));
    tmax = fmaxf(tmax, __shfl_xor(tmax, 32, 64));
    const float mnew = fmaxf(mrow, tmax);
    const float fsc = __builtin_exp2f(mrow - mnew);
    mrow = mnew;
    float tsum = 0.f;
#pragma unroll
    for (int j = 0; j < 4; j++)
#pragma unroll
      for (int r = 0; r < 4; r++) {
        const float p = __builtin_exp2f(sc[j][r] - mnew);
        sc[j][r] = p;
        tsum += p;
      }
    tsum += __shfl_xor(tsum, 16, 64);
    tsum += __shfl_xor(tsum, 32, 64);
    lrow = lrow * fsc + tsum;

#pragma unroll
    for (int j = 0; j < 4; j++) {
      bf16x4 w;
#pragma unroll
      for (int r = 0; r < 4; r++) w[r] = (bf16_t)sc[j][r];
      const int pbyte = lr * 128 + ((j * 32 + lg * 8) ^ ((lr & 7) << 4));
      *(bf16x4*)((char*)&Ps[wid][0] + pbyte) = w;
    }
    float fr[4];
#pragma unroll
    for (int r = 0; r < 4; r++) fr[r] = __shfl(fsc, sbl | (lg * 4 + r), 64);
#pragma unroll
    for (int dt = 0; dt < 4; dt++)
#pragma unroll
      for (int r = 0; r < 4; r++) Ot[dt][r] *= fr[r];
    __builtin_amdgcn_s_setprio(1);
#pragma unroll
    for (int c = 0; c < 2; c++) {
      const int abyte = lr * 128 + ((c * 64 + lg * 16) ^ ((lr & 7) << 4));
      bf16x8 pa = *(const bf16x8*)((const char*)&Ps[wid][0] + abyte);
#pragma unroll
      for (int dt = 0; dt < 4; dt++) {
        const int d = dt * 16 + lr;
        const int f = (d & 7) ^ ((d >> 3) & 7);
        const int vbyte = d * 128 + (((c * 4 + lg) * 16) ^ (f << 4));
        bf16x8 bv = *(const bf16x8*)((const char*)&Vst[cur][0] + vbyte);
        Ot[dt] = __builtin_amdgcn_mfma_f32_16x16x32_bf16(pa, bv, Ot[dt], 0, 0, 0);
      }
    }
    __builtin_amdgcn_s_setprio(0);
    vc0 = vn0; vc1 = vn1;
  }

  if (ns == 1) {
    float linv[4];
#pragma unroll
    for (int r = 0; r < 4; r++)
      linv[r] = 1.f / __shfl(lrow, sbl | (lg * 4 + r), 64);
    const int b = bh >> 4, h = bh & 15;
#pragma unroll
    for (int r = 0; r < 4; r++) {
      const int s = q0w + lg * 4 + r;
      const size_t base = ((size_t)(b * S_DIM + s)) * E_DIM + h * DH_DIM;
#pragma unroll
      for (int dt = 0; dt < 4; dt++)
        O[base + dt * 16 + lr] = (bf16_t)(Ot[dt][r] * linv[r]);
    }
  } else {
    const int sbase = (qt < 16) ? 8 + 2 * (qt - 8)
                     : (qt < 24) ? 24 + 3 * (qt - 16) : 48 + 4 * (qt - 24);
    const int slot = bh * 80 + sbase + sp;
    bf16_t* Ob = Opart + (size_t)slot * 64 * 64;
#pragma unroll
    for (int r = 0; r < 4; r++)
#pragma unroll
      for (int dt = 0; dt < 4; dt++)
        Ob[(wid * 16 + lg * 4 + r) * 64 + dt * 16 + lr] = (bf16_t)Ot[dt][r];
    if (lg == 0) {
      mpart[slot * 64 + wid * 16 + lr] = mrow;
      lpart[slot * 64 + wid * 16 + lr] = lrow;
    }
  }
}

// ---------------- combine partials for qt >= 8 -------------------------------------
__global__ __launch_bounds__(256) void attn_combine(
    const bf16_t* __restrict__ Opart, const float* __restrict__ mpart,
    const float* __restrict__ lpart, bf16_t* __restrict__ O)
{
  const int qt = 8 + blockIdx.x;
  const int bh = blockIdx.y;
  const int ns = (qt < 16) ? 2 : (qt < 24) ? 3 : 4;
  const int sbase = (qt < 16) ? 8 + 2 * (qt - 8)
                   : (qt < 24) ? 24 + 3 * (qt - 16) : 48 + 4 * (qt - 24);
  const int slot0 = bh * 80 + sbase;
  const int tid = threadIdx.x;
  const int q = tid >> 2, d0 = (tid & 3) * 16;

  float M = -1e30f;
  for (int s = 0; s < ns; s++) M = fmaxf(M, mpart[(slot0 + s) * 64 + q]);
  float L = 0.f;
  float acc[16];
#pragma unroll
  for (int j = 0; j < 16; j++) acc[j] = 0.f;
  for (int s = 0; s < ns; s++) {
    const float w = __builtin_exp2f(mpart[(slot0 + s) * 64 + q] - M);
    L += w * lpart[(slot0 + s) * 64 + q];
    const bf16_t* Ob = Opart + ((size_t)(slot0 + s) * 64 + q) * 64 + d0;
    bf16x8 o0 = *(const bf16x8*)Ob;
    bf16x8 o1 = *(const bf16x8*)(Ob + 8);
#pragma unroll
    for (int j = 0; j < 8; j++) { acc[j] += w * (float)o0[j]; acc[8 + j] += w * (float)o1[j]; }
  }
  const float inv = 1.f / L;
  const int b = bh >> 4, h = bh & 15;
  const int srow = qt * 64 + q;
  bf16_t* out = O + ((size_t)(b * S_DIM + srow)) * E_DIM + h * DH_DIM + d0;
  bf16x8 w0, w1;
#pragma unroll
  for (int j = 0; j < 8; j++) { w0[j] = (bf16_t)(acc[j] * inv); w1[j] = (bf16_t)(acc[8 + j] * inv); }
  *(bf16x8*)out = w0;
  *(bf16x8*)(out + 8) = w1;
}

// ---------------- launcher ---------------------------------------------------------
extern "C" void kernel_launch(void* const* d_in, const int* in_sizes, int n_in,
                              void* d_out, int out_size, void* d_ws, size_t ws_size,
                              hipStream_t stream)
{
  const float* x    = (const float*)d_in[0];
  const float* ln1g = (const float*)d_in[1];
  const float* ln1b = (const float*)d_in[2];
  const float* Wq   = (const float*)d_in[3];
  const float* Wk   = (const float*)d_in[4];
  const float* Wv   = (const float*)d_in[5];
  const float* Wo   = (const float*)d_in[6];
  const float* bo   = (const float*)d_in[7];
  const float* ln2g = (const float*)d_in[8];
  const float* ln2b = (const float*)d_in[9];
  const float* W1   = (const float*)d_in[10];
  const float* b1   = (const float*)d_in[11];
  const float* W2   = (const float*)d_in[12];
  const float* b2   = (const float*)d_in[13];

  char* ws = (char*)d_ws;
  bf16_t* WqkvT = (bf16_t*)(ws + 0);          //  6.29 MB  [3072][1024] (dead after QKV)
  bf16_t* WoT   = (bf16_t*)(ws + 6291456);    //  2.10 MB  (dead after O-proj)
  bf16_t* W1T   = (bf16_t*)(ws + 8388608);    //  8.39 MB  (dead after FFN1)
  bf16_t* W2T   = (bf16_t*)(ws + 16777216);   //  8.39 MB
  bf16_t* h1    = (bf16_t*)(ws + 25165824);   //  8.39 MB  (dead after QKV)
  bf16_t* qb    = (bf16_t*)(ws + 33554432);   //  8.39 MB  (dead after attn)
  bf16_t* kb    = (bf16_t*)(ws + 41943040);   //  8.39 MB
  bf16_t* vb    = (bf16_t*)(ws + 50331648);   //  8.39 MB
  bf16_t* attnb = (bf16_t*)(ws + 58720256);   //  8.39 MB  (dead after O-proj)
  float*  xmid  = (float* )(ws + 67108864);   // 16.78 MB  f32
  bf16_t* h2    = (bf16_t*)(ws + 83886080);   //  8.39 MB  (dead after FFN1)
  bf16_t* ff1   = (bf16_t*)(ws + 25165824);   // 33.55 MB  over h1/qb/kb/vb (dead by FFN1)
  // attn partials: live attn->combine only; Opart overlaps xmid+h2 (written later)
  bf16_t* Opart = (bf16_t*)(ws + 67108864);   // 20.97 MB
  float*  mpart = (float* )(ws + 25165824);   //  0.66 MB (over h1, dead)
  float*  lpart = (float* )(ws + 25821184);   //  0.66 MB
  // O-proj split-K f32 partials [2][4096][1024]: over h1/qb/kb/vb (dead at O-proj)
  float*  po    = (float* )(ws + 25165824);   // 33.55 MB, consumed by reduce2_ln
  // FFN2 split-K bf16 partials [4096][1024] x4: over dead regions at FFN2 time
  bf16_t* pf0   = (bf16_t*)(ws + 0);          // over WqkvT+WoT
  bf16_t* pf1   = (bf16_t*)(ws + 8388608);    // over W1T
  bf16_t* pf2   = (bf16_t*)(ws + 58720256);   // over attnb
  bf16_t* pf3   = (bf16_t*)(ws + 83886080);   // over h2

  qkv_transpose<<<dim3(16, 48), 256, 0, stream>>>(Wq, Wk, Wv, WqkvT);
  transpose_cast<<<dim3(16, 16), 256, 0, stream>>>(Wo, WoT, 1024, 1024);
  transpose_cast<<<dim3(64, 16), 256, 0, stream>>>(W1, W1T, 1024, 4096);
  transpose_cast<<<dim3(16, 64), 256, 0, stream>>>(W2, W2T, 4096, 1024);

  ln_kernel<<<4096, 256, 0, stream>>>(x, ln1g, ln1b, h1);
  gemm_kernel<EPI_QKV><<<dim3(32, 24, 1), 256, 0, stream>>>(
      h1, WqkvT, 4096, 3072, 1024, 1024, nullptr, nullptr,
      nullptr, nullptr, qb, kb, vb);
  attn_kernel<<<dim3(80, 32), 256, 0, stream>>>(qb, kb, vb, attnb, Opart, mpart, lpart);
  attn_combine<<<dim3(24, 32), 256, 0, stream>>>(Opart, mpart, lpart, attnb);
  gemm_kernel<EPI_PART_F32><<<dim3(32, 8, 2), 256, 0, stream>>>(
      attnb, WoT, 4096, 1024, 1024, 512, nullptr, nullptr,
      po, nullptr, nullptr, nullptr, nullptr);
  reduce2_ln<<<4096, 256, 0, stream>>>(po, bo, x, ln2g, ln2b, xmid, h2);
  gemm_kernel<EPI_BIAS_RELU><<<dim3(32, 32, 1), 256, 0, stream>>>(
      h2, W1T, 4096, 4096, 1024, 1024, b1, nullptr,
      nullptr, ff1, nullptr, nullptr, nullptr);
  gemm_kernel<EPI_PART_B16><<<dim3(32, 8, 4), 256, 0, stream>>>(
      ff1, W2T, 4096, 1024, 4096, 1024, nullptr, nullptr,
      nullptr, pf0, pf1, pf2, pf3);
  reduce4<<<4096, 256, 0, stream>>>(pf0, pf1, pf2, pf3, b2, xmid, (float*)d_out);

  (void)in_sizes; (void)n_in; (void)out_size; (void)ws_size;
}